// Round 1
// baseline (378.195 us; speedup 1.0000x reference)
//
#include <hip/hip_runtime.h>
#include <hip/hip_bf16.h>

// AFT-Full on gfx950. Pipeline:
//  prep (cast/transpose/exp) -> GEMM1 (x @ [Wq|Wk|Wv], epilogue sig/exp) ->
//  fill_z (transpose to [j][s], interleave eKV/eK) -> GEMM2 (ew @ Z, batched b) ->
//  combine (q_sig*num/den) -> GEMM3 (@Wo + bo).
// All GEMMs: f16 MFMA 16x16x32, 128x128 tile, BK=32, global_load_lds w=16,
// XOR-swizzled LDS so fragment ds_read_b128 is 2-way-bank-conflict (free).

#define AS1(p) ((const __attribute__((address_space(1))) void*)(p))
#define AS3(p) ((__attribute__((address_space(3))) void*)(p))

typedef _Float16 half8 __attribute__((ext_vector_type(8)));
typedef _Float16 half4v __attribute__((ext_vector_type(4)));
typedef _Float16 half2v __attribute__((ext_vector_type(2)));
typedef float floatx4 __attribute__((ext_vector_type(4)));

// ---------------- prep kernels ----------------

__global__ void cast_f32_to_f16(const float* __restrict__ src, _Float16* __restrict__ dst, int n4) {
  int i = blockIdx.x * blockDim.x + threadIdx.x;
  if (i >= n4) return;
  float4 v = ((const float4*)src)[i];
  half4v h;
  h.x = (_Float16)v.x; h.y = (_Float16)v.y; h.z = (_Float16)v.z; h.w = (_Float16)v.w;
  ((half4v*)dst)[i] = h;
}

__global__ void exp_f32_to_f16(const float* __restrict__ src, _Float16* __restrict__ dst, int n4) {
  int i = blockIdx.x * blockDim.x + threadIdx.x;
  if (i >= n4) return;
  float4 v = ((const float4*)src)[i];
  half4v h;
  h.x = (_Float16)__expf(v.x); h.y = (_Float16)__expf(v.y);
  h.z = (_Float16)__expf(v.z); h.w = (_Float16)__expf(v.w);
  ((half4v*)dst)[i] = h;
}

// transpose+cast 1024x1024 f32 -> f16; z selects Wq/Wk/Wv (-> dqkv rows 0/1024/2048) or Wo (-> dwo)
__global__ void transpose_cast_w(const float* __restrict__ w0, const float* __restrict__ w1,
                                 const float* __restrict__ w2, const float* __restrict__ w3,
                                 _Float16* __restrict__ dqkv, _Float16* __restrict__ dwo) {
  const float* src = blockIdx.z == 0 ? w0 : blockIdx.z == 1 ? w1 : blockIdx.z == 2 ? w2 : w3;
  _Float16* dst = (blockIdx.z < 3) ? (dqkv + (size_t)blockIdx.z * 1024 * 1024) : dwo;
  __shared__ float tile[32][33];
  const int r0 = blockIdx.x * 32, c0 = blockIdx.y * 32;
  const int tr = threadIdx.x >> 5, tc = threadIdx.x & 31;
#pragma unroll
  for (int p = 0; p < 4; ++p) {
    int rr = tr + p * 8;
    tile[rr][tc] = src[(size_t)(r0 + rr) * 1024 + c0 + tc];
  }
  __syncthreads();
#pragma unroll
  for (int p = 0; p < 4; ++p) {
    int rr = tr + p * 8;  // column within source tile
    dst[(size_t)(c0 + rr) * 1024 + r0 + tc] = (_Float16)tile[tc][rr];
  }
}

// ---------------- main GEMM: C[M,N] = A[M,K] @ Bt[N,K]^T ----------------
// MODE 0: QKV epilogue -> f16, cols [0,1024) sigmoid(+bq), [1024,2048) exp(+bk), rest +bv
// MODE 1: plain f16 store
// MODE 2: fp32 store + bias0
template <int MODE>
__global__ __launch_bounds__(256) void gemm_bt(
    const _Float16* __restrict__ A, const _Float16* __restrict__ Bt, void* __restrict__ Cv,
    int M, int N, int K, long batchB, long batchCbytes,
    const float* __restrict__ bias0, const float* __restrict__ bias1,
    const float* __restrict__ bias2) {
  __shared__ __align__(16) _Float16 sA[4096];  // 128 x 32
  __shared__ __align__(16) _Float16 sB[4096];  // 128 x 32
  const int tid = threadIdx.x;
  const int wave = tid >> 6, lane = tid & 63;
  const int quad = lane >> 4, l16 = lane & 15;
  const int m0 = blockIdx.x * 128, n0 = blockIdx.y * 128;
  Bt += (long)blockIdx.z * batchB;
  char* Cb = (char*)Cv + (long)blockIdx.z * batchCbytes;

  // staging: flat byte offset f = (chunk*256 + tid)*16; row = f>>6 (64B row), kquad swizzled
  const int r0 = tid >> 2;
  const int q0 = (tid & 3) ^ ((r0 >> 1) & 3);
  const int r1 = r0 + 64;
  const int q1 = (tid & 3) ^ ((r1 >> 1) & 3);
  const _Float16* gA0 = A + (long)(m0 + r0) * K + q0 * 8;
  const _Float16* gA1 = A + (long)(m0 + r1) * K + q1 * 8;
  const _Float16* gB0 = Bt + (long)(n0 + r0) * K + q0 * 8;
  const _Float16* gB1 = Bt + (long)(n0 + r1) * K + q1 * 8;
  _Float16* sAw0 = sA + wave * 512;
  _Float16* sAw1 = sA + 2048 + wave * 512;
  _Float16* sBw0 = sB + wave * 512;
  _Float16* sBw1 = sB + 2048 + wave * 512;

  const int wm = (wave >> 1) * 64, wn = (wave & 1) * 64;
  int offA[4], offB[4];
#pragma unroll
  for (int i = 0; i < 4; ++i) {
    int ra = wm + i * 16 + l16;
    offA[i] = ra * 32 + (quad ^ ((ra >> 1) & 3)) * 8;
    int rb = wn + i * 16 + l16;
    offB[i] = rb * 32 + (quad ^ ((rb >> 1) & 3)) * 8;
  }

  floatx4 acc[4][4] = {};

  for (int k0 = 0; k0 < K; k0 += 32) {
    __builtin_amdgcn_global_load_lds(AS1(gA0 + k0), AS3(sAw0), 16, 0, 0);
    __builtin_amdgcn_global_load_lds(AS1(gA1 + k0), AS3(sAw1), 16, 0, 0);
    __builtin_amdgcn_global_load_lds(AS1(gB0 + k0), AS3(sBw0), 16, 0, 0);
    __builtin_amdgcn_global_load_lds(AS1(gB1 + k0), AS3(sBw1), 16, 0, 0);
    __syncthreads();
    half8 af[4], bf[4];
#pragma unroll
    for (int i = 0; i < 4; ++i) af[i] = *(const half8*)(sA + offA[i]);
#pragma unroll
    for (int i = 0; i < 4; ++i) bf[i] = *(const half8*)(sB + offB[i]);
#pragma unroll
    for (int mt = 0; mt < 4; ++mt)
#pragma unroll
      for (int nt = 0; nt < 4; ++nt)
        acc[mt][nt] = __builtin_amdgcn_mfma_f32_16x16x32_f16(af[mt], bf[nt], acc[mt][nt], 0, 0, 0);
    __syncthreads();
  }

#pragma unroll
  for (int mt = 0; mt < 4; ++mt) {
#pragma unroll
    for (int nt = 0; nt < 4; ++nt) {
      const int col = n0 + wn + nt * 16 + l16;
#pragma unroll
      for (int r = 0; r < 4; ++r) {
        const int row = m0 + wm + mt * 16 + quad * 4 + r;
        float v = acc[mt][nt][r];
        if (MODE == 0) {
          float o;
          if (col < 1024) {
            v += bias0[col];
            o = 1.0f / (1.0f + __expf(-v));
          } else if (col < 2048) {
            v += bias1[col - 1024];
            o = __expf(v);
          } else {
            v += bias2[col - 2048];
            o = v;
          }
          ((_Float16*)Cb)[(long)row * N + col] = (_Float16)o;
        } else if (MODE == 1) {
          ((_Float16*)Cb)[(long)row * N + col] = (_Float16)v;
        } else {
          ((float*)Cb)[(long)row * N + col] = v + bias0[col];
        }
      }
    }
  }
}

// ---------------- build Zt[b][j][s]: j=2c+0 -> eK*V, j=2c+1 -> eK ----------------
__global__ void fill_z(const _Float16* __restrict__ QKVe, _Float16* __restrict__ Zt) {
  __shared__ _Float16 lds_z[64][66];
  const int t = threadIdx.x;
  const int b = blockIdx.z;
  const int s0 = blockIdx.x * 64, c0 = blockIdx.y * 32;
  const int c2 = (t & 15) * 2;
#pragma unroll
  for (int i = 0; i < 4; ++i) {
    int sl = (t >> 4) + i * 16;
    const size_t rowoff = (size_t)(b * 2048 + s0 + sl) * 3072;
    half2v ek2 = *(const half2v*)(QKVe + rowoff + 1024 + c0 + c2);
    half2v v2 = *(const half2v*)(QKVe + rowoff + 2048 + c0 + c2);
    lds_z[2 * c2 + 0][sl] = (_Float16)((float)ek2[0] * (float)v2[0]);
    lds_z[2 * c2 + 1][sl] = ek2[0];
    lds_z[2 * c2 + 2][sl] = (_Float16)((float)ek2[1] * (float)v2[1]);
    lds_z[2 * c2 + 3][sl] = ek2[1];
  }
  __syncthreads();
  const int sl2 = (t & 31) * 2;
#pragma unroll
  for (int p = 0; p < 8; ++p) {
    int jj = p * 8 + (t >> 5);
    half2v v;
    v[0] = lds_z[jj][sl2];
    v[1] = lds_z[jj][sl2 + 1];
    *(half2v*)(Zt + ((size_t)b * 2048 + 2 * c0 + jj) * 2048 + s0 + sl2) = v;
  }
}

// ---------------- combine: OutHead = q_sig * num / den ----------------
__global__ void combine_out(const _Float16* __restrict__ C2, const _Float16* __restrict__ QKVe,
                            _Float16* __restrict__ OutHead) {
  int g = blockIdx.x * blockDim.x + threadIdx.x;  // 8192*512 threads
  int r = g >> 9;
  int c = (g & 511) * 2;
  half4v nd = *(const half4v*)(C2 + (size_t)r * 2048 + 2 * c);
  half2v q = *(const half2v*)(QKVe + (size_t)r * 3072 + c);
  half2v o;
  o[0] = (_Float16)((float)q[0] * (float)nd[0] / (float)nd[1]);
  o[1] = (_Float16)((float)q[1] * (float)nd[2] / (float)nd[3]);
  *(half2v*)(OutHead + (size_t)r * 1024 + c) = o;
}

// ---------------- launch ----------------
extern "C" void kernel_launch(void* const* d_in, const int* in_sizes, int n_in, void* d_out,
                              int out_size, void* d_ws, size_t ws_size, hipStream_t stream) {
  const float* x = (const float*)d_in[0];
  const float* Wq = (const float*)d_in[1];
  const float* bq = (const float*)d_in[2];
  const float* Wk = (const float*)d_in[3];
  const float* bk = (const float*)d_in[4];
  const float* Wv = (const float*)d_in[5];
  const float* bv = (const float*)d_in[6];
  const float* Wo = (const float*)d_in[7];
  const float* bo = (const float*)d_in[8];
  const float* wb = (const float*)d_in[9];

  char* ws = (char*)d_ws;
  _Float16* x_h = (_Float16*)(ws + 0);              // 16,777,216 B
  _Float16* WqkvT = (_Float16*)(ws + 16777216);     //  6,291,456 B
  _Float16* WoT = (_Float16*)(ws + 23068672);       //  2,097,152 B
  _Float16* ew_h = (_Float16*)(ws + 25165824);      //  8,388,608 B
  _Float16* QKVe = (_Float16*)(ws + 33554432);      // 50,331,648 B
  _Float16* Zt = (_Float16*)(ws + 83886080);        // 33,554,432 B
  _Float16* C2 = (_Float16*)(ws + 117440512);       // 33,554,432 B
  _Float16* OutHead = (_Float16*)(ws + 150994944);  // 16,777,216 B -> 167,772,160 total

  // prep
  cast_f32_to_f16<<<8192, 256, 0, stream>>>(x, x_h, 2097152);
  transpose_cast_w<<<dim3(32, 32, 4), 256, 0, stream>>>(Wq, Wk, Wv, Wo, WqkvT, WoT);
  exp_f32_to_f16<<<4096, 256, 0, stream>>>(wb, ew_h, 1048576);

  // GEMM1: QKVe[8192,3072] = x @ [Wq|Wk|Wv] (+bias, sigmoid/exp epilogue)
  gemm_bt<0><<<dim3(64, 24, 1), 256, 0, stream>>>(x_h, WqkvT, QKVe, 8192, 3072, 1024, 0, 0, bq,
                                                  bk, bv);

  // Zt[b][2048][2048]
  fill_z<<<dim3(32, 32, 4), 256, 0, stream>>>(QKVe, Zt);

  // GEMM2: C2[b] = ew @ Zt[b]^T  (batched over b)
  gemm_bt<1><<<dim3(16, 16, 4), 256, 0, stream>>>(ew_h, Zt, C2, 2048, 2048, 2048,
                                                  (long)2048 * 2048, (long)2048 * 2048 * 2,
                                                  nullptr, nullptr, nullptr);

  // OutHead = q_sig * num/den
  combine_out<<<16384, 256, 0, stream>>>(C2, QKVe, OutHead);

  // GEMM3: out = OutHead @ Wo + bo (fp32)
  gemm_bt<2><<<dim3(64, 8, 1), 256, 0, stream>>>(OutHead, WoT, d_out, 8192, 1024, 1024, 0, 0, bo,
                                                 nullptr, nullptr);
}

// Round 2
// 329.519 us; speedup vs baseline: 1.1477x; 1.1477x over previous
//
#include <hip/hip_runtime.h>
#include <hip/hip_bf16.h>

// AFT-Full on gfx950. Pipeline:
//  prep (cast x + exp wbias, transpose W) -> GEMM1 (x @ [Wq|Wk|Wv], epilogue sig/exp) ->
//  fill_z (transpose to [j][s], group-16 interleave of eKV/eK) ->
//  GEMM2 (ew @ Zt^T, fused q_sig*num/den epilogue -> OutHead) -> GEMM3 (@Wo + bo).
// GEMMs: f16 MFMA 16x16x32, 128x128 tile, BK=64 (one barrier pair per 64 K),
// global_load_lds w=16, XOR-swizzled LDS rows (128B) so ds_read_b128 is 2-way (free).

#define AS1(p) ((const __attribute__((address_space(1))) void*)(p))
#define AS3(p) ((__attribute__((address_space(3))) void*)(p))

typedef _Float16 half8 __attribute__((ext_vector_type(8)));
typedef _Float16 half4v __attribute__((ext_vector_type(4)));
typedef _Float16 half2v __attribute__((ext_vector_type(2)));
typedef float floatx4 __attribute__((ext_vector_type(4)));

// ---------------- prep: cast x -> f16 and exp(wbias) -> f16, one launch ----------------
__global__ void prep_cast_exp(const float* __restrict__ x, const float* __restrict__ wb,
                              _Float16* __restrict__ x_h, _Float16* __restrict__ ew_h) {
  int i = blockIdx.x * 256 + threadIdx.x;
  if (i < 2097152) {  // x: 8388608 f32 = 2097152 float4
    float4 v = ((const float4*)x)[i];
    half4v h;
    h.x = (_Float16)v.x; h.y = (_Float16)v.y; h.z = (_Float16)v.z; h.w = (_Float16)v.w;
    ((half4v*)x_h)[i] = h;
  } else {  // wbias: 4194304 f32 = 1048576 float4
    int j = i - 2097152;
    float4 v = ((const float4*)wb)[j];
    half4v h;
    h.x = (_Float16)__expf(v.x); h.y = (_Float16)__expf(v.y);
    h.z = (_Float16)__expf(v.z); h.w = (_Float16)__expf(v.w);
    ((half4v*)ew_h)[j] = h;
  }
}

// transpose+cast 1024x1024 f32 -> f16; z selects Wq/Wk/Wv (-> dqkv rows 0/1024/2048) or Wo (-> dwo)
__global__ void transpose_cast_w(const float* __restrict__ w0, const float* __restrict__ w1,
                                 const float* __restrict__ w2, const float* __restrict__ w3,
                                 _Float16* __restrict__ dqkv, _Float16* __restrict__ dwo) {
  const float* src = blockIdx.z == 0 ? w0 : blockIdx.z == 1 ? w1 : blockIdx.z == 2 ? w2 : w3;
  _Float16* dst = (blockIdx.z < 3) ? (dqkv + (size_t)blockIdx.z * 1024 * 1024) : dwo;
  __shared__ float tile[32][33];
  const int r0 = blockIdx.x * 32, c0 = blockIdx.y * 32;
  const int tr = threadIdx.x >> 5, tc = threadIdx.x & 31;
#pragma unroll
  for (int p = 0; p < 4; ++p) {
    int rr = tr + p * 8;
    tile[rr][tc] = src[(size_t)(r0 + rr) * 1024 + c0 + tc];
  }
  __syncthreads();
#pragma unroll
  for (int p = 0; p < 4; ++p) {
    int rr = tr + p * 8;
    dst[(size_t)(c0 + rr) * 1024 + r0 + tc] = (_Float16)tile[tc][rr];
  }
}

// ---------------- main GEMM: C[M,N] = A[M,K] @ Bt[N,K]^T, BK=64 ----------------
// MODE 0: QKV epilogue -> f16; cols [0,1024) sigmoid(+bq), [1024,2048) exp(+bk), rest +bv
// MODE 2: fp32 store + bias0
// MODE 3: fused AFT combine: acc cols are (num|den) in 16-col groups; writes
//         OutHead[row*1024 + ch] = Qsig[row*3072+ch] * num/den  (f16, ldc=1024)
template <int MODE>
__global__ __launch_bounds__(256) void gemm_bt(
    const _Float16* __restrict__ A, const _Float16* __restrict__ Bt, void* __restrict__ Cv,
    int M, int N, int K, long batchB, long batchCbytes,
    const float* __restrict__ bias0, const float* __restrict__ bias1,
    const float* __restrict__ bias2, const _Float16* __restrict__ Qsig, long batchQ) {
  __shared__ __align__(16) _Float16 sA[8192];  // 128 x 64
  __shared__ __align__(16) _Float16 sB[8192];  // 128 x 64
  const int tid = threadIdx.x;
  const int wave = tid >> 6, lane = tid & 63;
  const int quad = lane >> 4, l16 = lane & 15;
  const int m0 = blockIdx.x * 128, n0 = blockIdx.y * 128;
  Bt += (long)blockIdx.z * batchB;
  char* Cb = (char*)Cv + (long)blockIdx.z * batchCbytes;

  // staging: chunk c covers rows [c*32, c*32+32); each thread: row rs, 16B unit.
  // HW forces LDS slot = wave-base + lane*16, so we swizzle the GLOBAL k-unit:
  // logical unit u lives at phys slot u ^ (row&7).
  const int rs = tid >> 3;                    // 0..31 (row within chunk)
  const int ug = (tid & 7) ^ (rs & 7);        // global 16B k-unit to fetch
  const _Float16* gA = A + (long)(m0 + rs) * K + ug * 8;
  const _Float16* gB = Bt + (long)(n0 + rs) * K + ug * 8;
  _Float16* sAd = sA + wave * 512;  // + chunk*2048; +lane*8 implicit in HW
  _Float16* sBd = sB + wave * 512;

  const int wm = (wave >> 1) * 64, wn = (wave & 1) * 64;
  // fragment LDS offsets (halfs): row*64 + ((h*4+quad)^(row&7))*8
  int offA[2][4], offB[2][4];
#pragma unroll
  for (int h = 0; h < 2; ++h)
#pragma unroll
    for (int i = 0; i < 4; ++i) {
      int ra = wm + i * 16 + l16;
      offA[h][i] = ra * 64 + (((h * 4 + quad) ^ (ra & 7)) * 8);
      int rb = wn + i * 16 + l16;
      offB[h][i] = rb * 64 + (((h * 4 + quad) ^ (rb & 7)) * 8);
    }

  floatx4 acc[4][4] = {};

  for (int k0 = 0; k0 < K; k0 += 64) {
#pragma unroll
    for (int c = 0; c < 4; ++c)
      __builtin_amdgcn_global_load_lds(AS1(gA + (long)c * 32 * K + k0), AS3(sAd + c * 2048), 16, 0, 0);
#pragma unroll
    for (int c = 0; c < 4; ++c)
      __builtin_amdgcn_global_load_lds(AS1(gB + (long)c * 32 * K + k0), AS3(sBd + c * 2048), 16, 0, 0);
    __syncthreads();
#pragma unroll
    for (int h = 0; h < 2; ++h) {
      half8 af[4], bf[4];
#pragma unroll
      for (int i = 0; i < 4; ++i) af[i] = *(const half8*)(sA + offA[h][i]);
#pragma unroll
      for (int i = 0; i < 4; ++i) bf[i] = *(const half8*)(sB + offB[h][i]);
#pragma unroll
      for (int mt = 0; mt < 4; ++mt)
#pragma unroll
        for (int nt = 0; nt < 4; ++nt)
          acc[mt][nt] =
              __builtin_amdgcn_mfma_f32_16x16x32_f16(af[mt], bf[nt], acc[mt][nt], 0, 0, 0);
    }
    __syncthreads();
  }

  if (MODE == 3) {
    // wave covers j in [n0+wn, n0+wn+64) = 2 groups of 32 j (16 num cols + 16 den cols)
    const int gbase = (n0 + wn) >> 5;
    const _Float16* Q = Qsig + (long)blockIdx.z * batchQ;
#pragma unroll
    for (int mt = 0; mt < 4; ++mt) {
#pragma unroll
      for (int p = 0; p < 2; ++p) {
        const int ch = (gbase + p) * 16 + l16;  // output channel 0..1023
#pragma unroll
        for (int r = 0; r < 4; ++r) {
          const int row = m0 + wm + mt * 16 + quad * 4 + r;
          float num = acc[mt][2 * p][r];
          float den = acc[mt][2 * p + 1][r];
          float q = (float)Q[(long)row * 3072 + ch];
          ((_Float16*)Cb)[(long)row * 1024 + ch] = (_Float16)(q * num / den);
        }
      }
    }
    return;
  }

#pragma unroll
  for (int mt = 0; mt < 4; ++mt) {
#pragma unroll
    for (int nt = 0; nt < 4; ++nt) {
      const int col = n0 + wn + nt * 16 + l16;
#pragma unroll
      for (int r = 0; r < 4; ++r) {
        const int row = m0 + wm + mt * 16 + quad * 4 + r;
        float v = acc[mt][nt][r];
        if (MODE == 0) {
          float o;
          if (col < 1024) {
            v += bias0[col];
            o = 1.0f / (1.0f + __expf(-v));
          } else if (col < 2048) {
            v += bias1[col - 1024];
            o = __expf(v);
          } else {
            v += bias2[col - 2048];
            o = v;
          }
          ((_Float16*)Cb)[(long)row * N + col] = (_Float16)o;
        } else {
          ((float*)Cb)[(long)row * N + col] = v + bias0[col];
        }
      }
    }
  }
}

// ---------------- build Zt[b][j][s], group-16 interleave ----------------
// channel c (0..1023): g=c>>4, w=c&15; j_num = g*32+w (eK*V), j_den = g*32+16+w (eK)
__global__ void fill_z(const _Float16* __restrict__ QKVe, _Float16* __restrict__ Zt) {
  __shared__ _Float16 lds_z[64][66];
  const int t = threadIdx.x;
  const int b = blockIdx.z;
  const int s0 = blockIdx.x * 64, c0 = blockIdx.y * 32;
  const int c2 = (t & 15) * 2;  // local channel (even), block covers 32 channels
  const int lj = (c2 >> 4) * 32 + (c2 & 15);  // local num row for c2
#pragma unroll
  for (int i = 0; i < 4; ++i) {
    int sl = (t >> 4) + i * 16;
    const size_t rowoff = (size_t)(b * 2048 + s0 + sl) * 3072;
    half2v ek2 = *(const half2v*)(QKVe + rowoff + 1024 + c0 + c2);
    half2v v2 = *(const half2v*)(QKVe + rowoff + 2048 + c0 + c2);
    lds_z[lj + 0][sl] = (_Float16)((float)ek2[0] * (float)v2[0]);
    lds_z[lj + 1][sl] = (_Float16)((float)ek2[1] * (float)v2[1]);
    lds_z[lj + 16][sl] = ek2[0];
    lds_z[lj + 17][sl] = ek2[1];
  }
  __syncthreads();
  const int sl2 = (t & 31) * 2;
#pragma unroll
  for (int p = 0; p < 8; ++p) {
    int jj = p * 8 + (t >> 5);
    half2v v;
    v[0] = lds_z[jj][sl2];
    v[1] = lds_z[jj][sl2 + 1];
    *(half2v*)(Zt + ((size_t)b * 2048 + 2 * c0 + jj) * 2048 + s0 + sl2) = v;
  }
}

// ---------------- launch ----------------
extern "C" void kernel_launch(void* const* d_in, const int* in_sizes, int n_in, void* d_out,
                              int out_size, void* d_ws, size_t ws_size, hipStream_t stream) {
  const float* x = (const float*)d_in[0];
  const float* Wq = (const float*)d_in[1];
  const float* bq = (const float*)d_in[2];
  const float* Wk = (const float*)d_in[3];
  const float* bk = (const float*)d_in[4];
  const float* Wv = (const float*)d_in[5];
  const float* bv = (const float*)d_in[6];
  const float* Wo = (const float*)d_in[7];
  const float* bo = (const float*)d_in[8];
  const float* wb = (const float*)d_in[9];

  char* ws = (char*)d_ws;
  _Float16* x_h = (_Float16*)(ws + 0);              // 16,777,216 B
  _Float16* WqkvT = (_Float16*)(ws + 16777216);     //  6,291,456 B
  _Float16* WoT = (_Float16*)(ws + 23068672);       //  2,097,152 B
  _Float16* ew_h = (_Float16*)(ws + 25165824);      //  8,388,608 B
  _Float16* QKVe = (_Float16*)(ws + 33554432);      // 50,331,648 B
  _Float16* Zt = (_Float16*)(ws + 83886080);        // 33,554,432 B
  _Float16* OutHead = (_Float16*)(ws + 117440512);  // 16,777,216 B -> 134,217,728 total

  // prep
  prep_cast_exp<<<12288, 256, 0, stream>>>(x, wb, x_h, ew_h);
  transpose_cast_w<<<dim3(32, 32, 4), 256, 0, stream>>>(Wq, Wk, Wv, Wo, WqkvT, WoT);

  // GEMM1: QKVe[8192,3072] = x @ [Wq|Wk|Wv] (+bias, sigmoid/exp epilogue)
  gemm_bt<0><<<dim3(64, 24, 1), 256, 0, stream>>>(x_h, WqkvT, QKVe, 8192, 3072, 1024, 0, 0, bq,
                                                  bk, bv, nullptr, 0);

  // Zt[b][2048][2048], group-16 num/den interleave
  fill_z<<<dim3(32, 32, 4), 256, 0, stream>>>(QKVe, Zt);

  // GEMM2: fused  OutHead = q_sig * (ew@eKV)/(ew@eK)   (batched over b)
  gemm_bt<3><<<dim3(16, 16, 4), 256, 0, stream>>>(ew_h, Zt, OutHead, 2048, 2048, 2048,
                                                  (long)2048 * 2048, (long)2048 * 1024 * 2,
                                                  nullptr, nullptr, nullptr, QKVe,
                                                  (long)2048 * 3072);

  // GEMM3: out = OutHead @ Wo + bo (fp32)
  gemm_bt<2><<<dim3(64, 8, 1), 256, 0, stream>>>(OutHead, WoT, d_out, 8192, 1024, 1024, 0, 0, bo,
                                                 nullptr, nullptr, nullptr, 0);
}

// Round 4
// 301.988 us; speedup vs baseline: 1.2524x; 1.0912x over previous
//
#include <hip/hip_runtime.h>
#include <hip/hip_bf16.h>

// AFT-Full on gfx950. Pipeline (5 launches):
//  prep (cast x + exp wbias) ; transpose W (with KV channel-interleave reorder) ->
//  GEMM1 (x @ [Wq|Wkv-interleaved]; epilogue: Q->sigmoid->Qsig, K/V->eK,eKV->Zt[j][s]) ->
//  GEMM2 (ew @ Zt^T batched; fused q_sig*num/den epilogue -> OutHead) -> GEMM3 (@Wo + bo).
// GEMMs: f16 MFMA 32x32x16 (half the MFMA instr count of 16x16x32 for same FLOPs),
// 128x128 tile, BK=64, global_load_lds w=16, XOR-swizzled LDS rows (128B).
// NOTE (round-3 bug): epilogue row MUST include the wave row offset `wm` —
// fragment loads use wm; dropping it in stores makes waves 2,3 overwrite rows 0..63.

#define AS1(p) ((const __attribute__((address_space(1))) void*)(p))
#define AS3(p) ((__attribute__((address_space(3))) void*)(p))

typedef _Float16 half8 __attribute__((ext_vector_type(8)));
typedef _Float16 half4v __attribute__((ext_vector_type(4)));
typedef float floatx16 __attribute__((ext_vector_type(16)));

// ---------------- prep: cast x -> f16 and exp(wbias) -> f16, one launch ----------------
__global__ void prep_cast_exp(const float* __restrict__ x, const float* __restrict__ wb,
                              _Float16* __restrict__ x_h, _Float16* __restrict__ ew_h) {
  int i = blockIdx.x * 256 + threadIdx.x;
  if (i < 2097152) {  // x: 8388608 f32 = 2097152 float4
    float4 v = ((const float4*)x)[i];
    half4v h;
    h[0] = (_Float16)v.x; h[1] = (_Float16)v.y; h[2] = (_Float16)v.z; h[3] = (_Float16)v.w;
    ((half4v*)x_h)[i] = h;
  } else {  // wbias: 4194304 f32 = 1048576 float4
    int j = i - 2097152;
    float4 v = ((const float4*)wb)[j];
    half4v h;
    h[0] = (_Float16)__expf(v.x); h[1] = (_Float16)__expf(v.y);
    h[2] = (_Float16)__expf(v.z); h[3] = (_Float16)__expf(v.w);
    ((half4v*)ew_h)[j] = h;
  }
}

// transpose+cast 1024x1024 f32 -> f16.
// z=0: Wq -> WqkvT rows [0,1024)
// z=1: Wk col c -> WqkvT row 1024 + (c>>5)*64 + (c&31)        (K half of channel group)
// z=2: Wv col c -> WqkvT row 1024 + (c>>5)*64 + 32 + (c&31)   (V half, same group)
// z=3: Wo -> WoT
__global__ void transpose_cast_w(const float* __restrict__ w0, const float* __restrict__ w1,
                                 const float* __restrict__ w2, const float* __restrict__ w3,
                                 _Float16* __restrict__ dqkv, _Float16* __restrict__ dwo) {
  const int z = blockIdx.z;
  const float* src = z == 0 ? w0 : z == 1 ? w1 : z == 2 ? w2 : w3;
  __shared__ float tile[32][33];
  const int r0 = blockIdx.x * 32, c0 = blockIdx.y * 32;
  const int tr = threadIdx.x >> 5, tc = threadIdx.x & 31;
#pragma unroll
  for (int p = 0; p < 4; ++p) {
    int rr = tr + p * 8;
    tile[rr][tc] = src[(size_t)(r0 + rr) * 1024 + c0 + tc];
  }
  __syncthreads();
#pragma unroll
  for (int p = 0; p < 4; ++p) {
    int c = c0 + tr + p * 8;  // source column = output "channel"
    size_t jr;
    _Float16* dst;
    if (z == 0) { jr = c; dst = dqkv; }
    else if (z == 3) { jr = c; dst = dwo; }
    else { jr = 1024 + ((size_t)(c >> 5) << 6) + ((z == 2) ? 32 : 0) + (c & 31); dst = dqkv; }
    dst[jr * 1024 + r0 + tc] = (_Float16)tile[tc][tr + p * 8];
  }
}

// ---------------- main GEMM: C[M,N] = A[M,K] @ Bt[N,K]^T, BK=64, MFMA 32x32x16 ----------------
// MODE 0: GEMM1 epilogue. n0<1024: sigmoid(v+bq) -> Qsig[row*1024+col].
//         n0>=1024: nt0=K-proj, nt1=V-proj for channel ch; eK=exp(+bk), eKV=eK*(v+bv);
//         write Zt[b][g*64+l32][s] (num) and [+32] (den) as packed 4-row 8B stores.
// MODE 2: fp32 store + bias0 (GEMM3)
// MODE 3: GEMM2 fused combine: nt0=num, nt1=den for channel ch;
//         OutHead[row*1024+ch] = Qsig[row*1024+ch] * num/den.
template <int MODE>
__global__ __launch_bounds__(256) void gemm_bt(
    const _Float16* __restrict__ A, const _Float16* __restrict__ Bt, void* __restrict__ Cv,
    int M, int N, int K, long batchB, long batchCbytes,
    const float* __restrict__ bias0, const float* __restrict__ bias1,
    const float* __restrict__ bias2, const _Float16* __restrict__ Qsig, long batchQ,
    _Float16* __restrict__ Zt) {
  __shared__ __align__(16) _Float16 sA[8192];  // 128 x 64
  __shared__ __align__(16) _Float16 sB[8192];  // 128 x 64
  const int tid = threadIdx.x;
  const int wave = tid >> 6, lane = tid & 63;
  const int l32 = lane & 31, khalf = lane >> 5;
  const int m0 = blockIdx.x * 128, n0 = blockIdx.y * 128;
  Bt += (long)blockIdx.z * batchB;
  char* Cb = (char*)Cv + (long)blockIdx.z * batchCbytes;

  // staging: chunk c covers rows [c*32, c*32+32); thread -> row rs, 16B unit.
  // HW slot = wave-base + lane*16 -> swizzle the GLOBAL k-unit: logical u at phys u^(row&7).
  const int rs = tid >> 3;
  const int ug = (tid & 7) ^ (rs & 7);
  const _Float16* gA = A + (long)(m0 + rs) * K + ug * 8;
  const _Float16* gB = Bt + (long)(n0 + rs) * K + ug * 8;
  _Float16* sAd = sA + wave * 512;
  _Float16* sBd = sB + wave * 512;

  const int wm = (wave >> 1) * 64, wn = (wave & 1) * 64;

  floatx16 acc[2][2] = {};

  for (int k0 = 0; k0 < K; k0 += 64) {
#pragma unroll
    for (int c = 0; c < 4; ++c)
      __builtin_amdgcn_global_load_lds(AS1(gA + (long)c * 32 * K + k0), AS3(sAd + c * 2048), 16,
                                       0, 0);
#pragma unroll
    for (int c = 0; c < 4; ++c)
      __builtin_amdgcn_global_load_lds(AS1(gB + (long)c * 32 * K + k0), AS3(sBd + c * 2048), 16,
                                       0, 0);
    __syncthreads();
#pragma unroll
    for (int ks = 0; ks < 4; ++ks) {
      half8 af[2], bf[2];
#pragma unroll
      for (int i = 0; i < 2; ++i) {
        int ra = wm + i * 32 + l32;
        af[i] = *(const half8*)(sA + ra * 64 + (((ks * 2 + khalf) ^ (ra & 7)) * 8));
        int rb = wn + i * 32 + l32;
        bf[i] = *(const half8*)(sB + rb * 64 + (((ks * 2 + khalf) ^ (rb & 7)) * 8));
      }
#pragma unroll
      for (int mt = 0; mt < 2; ++mt)
#pragma unroll
        for (int nt = 0; nt < 2; ++nt)
          acc[mt][nt] =
              __builtin_amdgcn_mfma_f32_32x32x16_f16(af[mt], bf[nt], acc[mt][nt], 0, 0, 0);
    }
    __syncthreads();
  }

  if (MODE == 0) {
    if (n0 < 1024) {
      _Float16* Qs = (_Float16*)Cb;
#pragma unroll
      for (int mt = 0; mt < 2; ++mt)
#pragma unroll
        for (int nt = 0; nt < 2; ++nt) {
          const int col = n0 + wn + nt * 32 + l32;
          const float bb = bias0[col];
#pragma unroll
          for (int reg = 0; reg < 16; ++reg) {
            const int row = m0 + wm + mt * 32 + 4 * khalf + 8 * (reg >> 2) + (reg & 3);
            float v = acc[mt][nt][reg] + bb;
            Qs[(long)row * 1024 + col] = (_Float16)(1.0f / (1.0f + __expf(-v)));
          }
        }
    } else {
      const int g = (n0 - 1024 + wn) >> 6;  // channel group (32 channels)
      const int ch = g * 32 + l32;
      const float bkc = bias1[ch], bvc = bias2[ch];
#pragma unroll
      for (int mt = 0; mt < 2; ++mt) {
#pragma unroll
        for (int q = 0; q < 4; ++q) {
          half4v numv, denv;
#pragma unroll
          for (int r = 0; r < 4; ++r) {
            float ek = __expf(acc[mt][0][q * 4 + r] + bkc);
            float vv = acc[mt][1][q * 4 + r] + bvc;
            denv[r] = (_Float16)ek;
            numv[r] = (_Float16)(ek * vv);
          }
          const int row = m0 + wm + mt * 32 + 4 * khalf + 8 * q;  // +r packed in vector
          const int b = row >> 11, s = row & 2047;
          const size_t jb = ((size_t)b * 2048 + (size_t)g * 64 + l32) * 2048 + s;
          *(half4v*)(Zt + jb) = numv;                // j_num = g*64 + l32
          *(half4v*)(Zt + jb + 32 * 2048) = denv;    // j_den = +32
        }
      }
    }
    return;
  }

  if (MODE == 3) {
    const _Float16* Q = Qsig + (long)blockIdx.z * batchQ;
    const int ch = ((n0 + wn) >> 6) * 32 + l32;
#pragma unroll
    for (int mt = 0; mt < 2; ++mt)
#pragma unroll
      for (int reg = 0; reg < 16; ++reg) {
        const int row = m0 + wm + mt * 32 + 4 * khalf + 8 * (reg >> 2) + (reg & 3);
        float num = acc[mt][0][reg], den = acc[mt][1][reg];
        float qs = (float)Q[(long)row * 1024 + ch];
        ((_Float16*)Cb)[(long)row * 1024 + ch] = (_Float16)(qs * num / den);
      }
    return;
  }

  // MODE 2
#pragma unroll
  for (int mt = 0; mt < 2; ++mt)
#pragma unroll
    for (int nt = 0; nt < 2; ++nt) {
      const int col = n0 + wn + nt * 32 + l32;
      const float bb = bias0[col];
#pragma unroll
      for (int reg = 0; reg < 16; ++reg) {
        const int row = m0 + wm + mt * 32 + 4 * khalf + 8 * (reg >> 2) + (reg & 3);
        ((float*)Cb)[(long)row * N + col] = acc[mt][nt][reg] + bb;
      }
    }
}

// ---------------- launch ----------------
extern "C" void kernel_launch(void* const* d_in, const int* in_sizes, int n_in, void* d_out,
                              int out_size, void* d_ws, size_t ws_size, hipStream_t stream) {
  const float* x = (const float*)d_in[0];
  const float* Wq = (const float*)d_in[1];
  const float* bq = (const float*)d_in[2];
  const float* Wk = (const float*)d_in[3];
  const float* bk = (const float*)d_in[4];
  const float* Wv = (const float*)d_in[5];
  const float* bv = (const float*)d_in[6];
  const float* Wo = (const float*)d_in[7];
  const float* bo = (const float*)d_in[8];
  const float* wb = (const float*)d_in[9];

  char* ws = (char*)d_ws;
  _Float16* x_h = (_Float16*)(ws + 0);              // 16,777,216 B
  _Float16* WqkvT = (_Float16*)(ws + 16777216);     //  6,291,456 B
  _Float16* WoT = (_Float16*)(ws + 23068672);       //  2,097,152 B
  _Float16* ew_h = (_Float16*)(ws + 25165824);      //  8,388,608 B
  _Float16* Qsig = (_Float16*)(ws + 33554432);      // 16,777,216 B
  _Float16* Zt = (_Float16*)(ws + 50331648);        // 33,554,432 B
  _Float16* OutHead = (_Float16*)(ws + 83886080);   // 16,777,216 B -> 100,663,296 total

  // prep
  prep_cast_exp<<<12288, 256, 0, stream>>>(x, wb, x_h, ew_h);
  transpose_cast_w<<<dim3(32, 32, 4), 256, 0, stream>>>(Wq, Wk, Wv, Wo, WqkvT, WoT);

  // GEMM1: x @ [Wq|Wkv]; epilogue writes Qsig and Zt directly
  gemm_bt<0><<<dim3(64, 24, 1), 256, 0, stream>>>(x_h, WqkvT, Qsig, 8192, 3072, 1024, 0, 0, bq,
                                                  bk, bv, nullptr, 0, Zt);

  // GEMM2: fused  OutHead = q_sig * (ew@eKV)/(ew@eK)   (batched over b)
  gemm_bt<3><<<dim3(16, 16, 4), 256, 0, stream>>>(ew_h, Zt, OutHead, 2048, 2048, 2048,
                                                  (long)2048 * 2048, (long)2048 * 1024 * 2,
                                                  nullptr, nullptr, nullptr, Qsig,
                                                  (long)2048 * 1024, nullptr);

  // GEMM3: out = OutHead @ Wo + bo (fp32)
  gemm_bt<2><<<dim3(64, 8, 1), 256, 0, stream>>>(OutHead, WoT, d_out, 8192, 1024, 1024, 0, 0, bo,
                                                 nullptr, nullptr, nullptr, 0, nullptr);
}

// Round 5
// 301.668 us; speedup vs baseline: 1.2537x; 1.0011x over previous
//
#include <hip/hip_runtime.h>
#include <hip/hip_bf16.h>

// AFT-Full on gfx950 — fragment-linear edition.
// All GEMM operands are stored in GLOBAL memory pre-swizzled into 128x64
// "fragment-linear" tiles (16 KB) that exactly match the MFMA 32x32x16 read
// order. Staging global->LDS is then an identity copy (contiguous 1024-B
// chunks) and every ds_read_b128 is lane-sequential => zero bank conflicts
// (round-4 measured 4 conflict-cycles/read with 128-B-row + xor-swizzle).
// Pipeline (5 launches): prep_tiles (x->f16 tiles, exp(wbias)->tiles);
// transpose_cast_w (W^T -> tiles, KV channel-interleave); GEMM1 (epilogue:
// Qsig row-major + eK/eKV -> Zt tiles); GEMM2 (fused q_sig*num/den ->
// OutHead tiles); GEMM3 (-> fp32 out + bo).

#define AS1(p) ((const __attribute__((address_space(1))) void*)(p))
#define AS3(p) ((__attribute__((address_space(3))) void*)(p))

typedef _Float16 half8 __attribute__((ext_vector_type(8)));
typedef _Float16 half4v __attribute__((ext_vector_type(4)));
typedef float floatx16 __attribute__((ext_vector_type(16)));

// Offset (in halfs) of element (r, k) inside a 128x64 fragment-linear tile.
// Layout: [ri=r>>5][ks=k>>4][khalf=(k>>3)&1][l32=r&31][j=k&7]  (8192 halfs).
// A wave's af fragment (ri,ks) is then the contiguous 1024 B at
// (ri*4+ks)*512 + lane*8, with lane = khalf*32 + l32 (MFMA A-operand order).
__device__ __forceinline__ long frag_off(int r, int k) {
  return (long)(((((r >> 5) * 4 + (k >> 4)) * 2 + ((k >> 3) & 1)) * 32 + (r & 31)) * 8 + (k & 7));
}

// ---------------- prep: x -> f16 tiles; exp(wbias) -> f16 tiles ----------------
// blocks [0,1024): x tiles (64 tm x 16 tk, ld=1024); [1024,1536): ew tiles (16x32, ld=2048)
__global__ void prep_tiles(const float* __restrict__ x, const float* __restrict__ wb,
                           _Float16* __restrict__ x_h, _Float16* __restrict__ ew_h) {
  const int bid = blockIdx.x;
  const int tid = threadIdx.x;
  const bool isx = bid < 1024;
  const float* src;
  _Float16* dst;
  int tm, tk, ld, trel;
  if (isx) {
    trel = bid; tm = bid >> 4; tk = bid & 15; src = x; dst = x_h; ld = 1024;
  } else {
    trel = bid - 1024; tm = trel >> 5; tk = trel & 31; src = wb; dst = ew_h; ld = 2048;
  }
  const long tbase = (long)trel * 8192;
#pragma unroll
  for (int p = 0; p < 4; ++p) {
    const int s = p * 256 + tid;                       // tile slot (8 halfs each)
    const int r = ((s >> 8) << 5) + (s & 31);
    const int k = ((s >> 6) & 3) * 16 + ((s >> 5) & 1) * 8;
    const float* sp = src + (long)(tm * 128 + r) * ld + tk * 64 + k;
    const float4 v0 = *(const float4*)sp;
    const float4 v1 = *(const float4*)(sp + 4);
    half8 h;
    if (isx) {
      h[0] = (_Float16)v0.x; h[1] = (_Float16)v0.y; h[2] = (_Float16)v0.z; h[3] = (_Float16)v0.w;
      h[4] = (_Float16)v1.x; h[5] = (_Float16)v1.y; h[6] = (_Float16)v1.z; h[7] = (_Float16)v1.w;
    } else {
      h[0] = (_Float16)__expf(v0.x); h[1] = (_Float16)__expf(v0.y);
      h[2] = (_Float16)__expf(v0.z); h[3] = (_Float16)__expf(v0.w);
      h[4] = (_Float16)__expf(v1.x); h[5] = (_Float16)__expf(v1.y);
      h[6] = (_Float16)__expf(v1.z); h[7] = (_Float16)__expf(v1.w);
    }
    *(half8*)(dst + tbase + (long)s * 8) = h;          // contiguous 16-B stores
  }
}

// transpose+cast W (1024x1024 f32, [k][ch]) -> fragment-linear B tiles [n][k].
// z=0: Wq -> WqkvT n-rows [0,1024)
// z=1: Wk ch c -> n-row 1024 + (c>>5)*64 + (c&31)       (K half of 32-ch group)
// z=2: Wv ch c -> n-row 1024 + (c>>5)*64 + 32 + (c&31)  (V half, same group)
// z=3: Wo -> WoT
__global__ void transpose_cast_w(const float* __restrict__ w0, const float* __restrict__ w1,
                                 const float* __restrict__ w2, const float* __restrict__ w3,
                                 _Float16* __restrict__ dqkv, _Float16* __restrict__ dwo) {
  const int z = blockIdx.z;
  const float* src = z == 0 ? w0 : z == 1 ? w1 : z == 2 ? w2 : w3;
  __shared__ float tile[32][33];
  const int r0 = blockIdx.x * 32, c0 = blockIdx.y * 32;  // r=k-in, c=channel
  const int tr = threadIdx.x >> 5, tc = threadIdx.x & 31;
#pragma unroll
  for (int p = 0; p < 4; ++p) {
    int rr = tr + p * 8;
    tile[rr][tc] = src[(size_t)(r0 + rr) * 1024 + c0 + tc];
  }
  __syncthreads();
#pragma unroll
  for (int p = 0; p < 4; ++p) {
    const int c = c0 + tr + p * 8;  // channel
    const int kk = r0 + tc;        // k index
    int jr;
    _Float16* dst;
    if (z == 0) { jr = c; dst = dqkv; }
    else if (z == 3) { jr = c; dst = dwo; }
    else { jr = 1024 + ((c >> 5) << 6) + ((z == 2) ? 32 : 0) + (c & 31); dst = dqkv; }
    const long addr = ((long)(jr >> 7) * 16 + (kk >> 6)) * 8192 + frag_off(jr & 127, kk & 63);
    dst[addr] = (_Float16)tile[tc][tr + p * 8];
  }
}

// ---------------- main GEMM on fragment-linear tiles, MFMA 32x32x16, BK=64 ----------------
// A: [Mtiles][Ktiles] tiles; Bt: [Ntiles][Ktiles] tiles (both 8192-half frag tiles).
// MODE 0 (GEMM1): n0<1024 -> Qsig row-major sigmoid(+bq); else K/V pair ->
//   eK=exp(+bk), eKV=eK*(v+bv) -> Zt frag tiles (num at j=g*64+l32, den +32).
// MODE 2 (GEMM3): fp32 row-major store + bias0.
// MODE 3 (GEMM2): num/den pair + Qsig -> OutHead frag tiles (A-op of GEMM3).
template <int MODE>
__global__ __launch_bounds__(256) void gemm_bt(
    const _Float16* __restrict__ A, const _Float16* __restrict__ Bt, void* __restrict__ Cv,
    int Ktiles, long batchB, const float* __restrict__ bias0, const float* __restrict__ bias1,
    const float* __restrict__ bias2, const _Float16* __restrict__ Qsig,
    _Float16* __restrict__ Zt) {
  __shared__ __align__(16) _Float16 sA[8192];
  __shared__ __align__(16) _Float16 sB[8192];
  const int tid = threadIdx.x;
  const int wave = tid >> 6, lane = tid & 63;
  const int l32 = lane & 31, khalf = lane >> 5;
  const int m0 = blockIdx.x * 128, n0 = blockIdx.y * 128;
  const int wm = (wave >> 1) * 64, wn = (wave & 1) * 64;

  const _Float16* Atile = A + (long)blockIdx.x * Ktiles * 8192;
  const _Float16* Btile = Bt + (long)blockIdx.z * batchB + (long)blockIdx.y * Ktiles * 8192;

  floatx16 acc[2][2] = {};

  for (int tk = 0; tk < Ktiles; ++tk) {
    const _Float16* As = Atile + tk * 8192 + wave * 512 + lane * 8;
    const _Float16* Bs = Btile + tk * 8192 + wave * 512 + lane * 8;
#pragma unroll
    for (int c = 0; c < 4; ++c) {
      __builtin_amdgcn_global_load_lds(AS1(As + c * 2048), AS3(sA + c * 2048 + wave * 512), 16, 0, 0);
      __builtin_amdgcn_global_load_lds(AS1(Bs + c * 2048), AS3(sB + c * 2048 + wave * 512), 16, 0, 0);
    }
    __syncthreads();
#pragma unroll
    for (int ks = 0; ks < 4; ++ks) {
      half8 af[2], bf[2];
#pragma unroll
      for (int i = 0; i < 2; ++i) {
        af[i] = *(const half8*)(sA + (((wm >> 5) + i) * 4 + ks) * 512 + lane * 8);
        bf[i] = *(const half8*)(sB + (((wn >> 5) + i) * 4 + ks) * 512 + lane * 8);
      }
#pragma unroll
      for (int mt = 0; mt < 2; ++mt)
#pragma unroll
        for (int nt = 0; nt < 2; ++nt)
          acc[mt][nt] =
              __builtin_amdgcn_mfma_f32_32x32x16_f16(af[mt], bf[nt], acc[mt][nt], 0, 0, 0);
    }
    __syncthreads();
  }

  if (MODE == 0) {
    if (n0 < 1024) {
      _Float16* Qs = (_Float16*)Cv;
#pragma unroll
      for (int mt = 0; mt < 2; ++mt)
#pragma unroll
        for (int nt = 0; nt < 2; ++nt) {
          const int col = n0 + wn + nt * 32 + l32;
          const float bb = bias0[col];
#pragma unroll
          for (int reg = 0; reg < 16; ++reg) {
            const int row = m0 + wm + mt * 32 + 4 * khalf + 8 * (reg >> 2) + (reg & 3);
            const float v = acc[mt][nt][reg] + bb;
            Qs[(long)row * 1024 + col] = (_Float16)(1.0f / (1.0f + __expf(-v)));
          }
        }
    } else {
      const int g = (n0 - 1024 + wn) >> 6;       // 32-channel group
      const int ch = g * 32 + l32;
      const float bkc = bias1[ch], bvc = bias2[ch];
      const int jn = g * 64 + l32;               // num row in Zt; den = jn+32 (= +2048 halfs)
      const long tnbase = (long)(jn >> 7) * 32 * 8192;   // Zt Ktiles = 32
#pragma unroll
      for (int mt = 0; mt < 2; ++mt) {
#pragma unroll
        for (int q = 0; q < 4; ++q) {
          half4v numv, denv;
#pragma unroll
          for (int rr = 0; rr < 4; ++rr) {
            const float ek = __expf(acc[mt][0][q * 4 + rr] + bkc);
            const float vv = acc[mt][1][q * 4 + rr] + bvc;
            denv[rr] = (_Float16)ek;
            numv[rr] = (_Float16)(ek * vv);
          }
          const int row = m0 + wm + mt * 32 + 4 * khalf + 8 * q;  // +rr in vector
          const int b = row >> 11, s = row & 2047;
          const long off = (long)b * 4194304 + tnbase + (long)(s >> 6) * 8192 +
                           frag_off(jn & 127, s & 63);
          *(half4v*)(Zt + off) = numv;
          *(half4v*)(Zt + off + 2048) = denv;
        }
      }
    }
    return;
  }

  if (MODE == 3) {
    const _Float16* Q = Qsig + (long)blockIdx.z * 2097152;  // 2048*1024
    const int ch = ((n0 + wn) >> 6) * 32 + l32;
    _Float16* OH = (_Float16*)Cv;
#pragma unroll
    for (int mt = 0; mt < 2; ++mt)
#pragma unroll
      for (int reg = 0; reg < 16; ++reg) {
        const int r = m0 + wm + mt * 32 + 4 * khalf + 8 * (reg >> 2) + (reg & 3);
        const float num = acc[mt][0][reg], den = acc[mt][1][reg];
        const float qs = (float)Q[(long)r * 1024 + ch];
        const int R = blockIdx.z * 2048 + r;     // global row for GEMM3's A
        const long off = ((long)(R >> 7) * 16 + (ch >> 6)) * 8192 + frag_off(R & 127, ch & 63);
        OH[off] = (_Float16)(qs * num / den);
      }
    return;
  }

  // MODE 2: fp32 row-major + bias0
#pragma unroll
  for (int mt = 0; mt < 2; ++mt)
#pragma unroll
    for (int nt = 0; nt < 2; ++nt) {
      const int col = n0 + wn + nt * 32 + l32;
      const float bb = bias0[col];
#pragma unroll
      for (int reg = 0; reg < 16; ++reg) {
        const int row = m0 + wm + mt * 32 + 4 * khalf + 8 * (reg >> 2) + (reg & 3);
        ((float*)Cv)[(long)row * 1024 + col] = acc[mt][nt][reg] + bb;
      }
    }
}

// ---------------- launch ----------------
extern "C" void kernel_launch(void* const* d_in, const int* in_sizes, int n_in, void* d_out,
                              int out_size, void* d_ws, size_t ws_size, hipStream_t stream) {
  const float* x = (const float*)d_in[0];
  const float* Wq = (const float*)d_in[1];
  const float* bq = (const float*)d_in[2];
  const float* Wk = (const float*)d_in[3];
  const float* bk = (const float*)d_in[4];
  const float* Wv = (const float*)d_in[5];
  const float* bv = (const float*)d_in[6];
  const float* Wo = (const float*)d_in[7];
  const float* bo = (const float*)d_in[8];
  const float* wb = (const float*)d_in[9];

  char* ws = (char*)d_ws;
  _Float16* x_h = (_Float16*)(ws + 0);              // 16 MB  (1024 tiles)
  _Float16* WqkvT = (_Float16*)(ws + 16777216);     //  6 MB  (384 tiles)
  _Float16* WoT = (_Float16*)(ws + 23068672);       //  2 MB  (128 tiles)
  _Float16* ew_h = (_Float16*)(ws + 25165824);      //  8 MB  (512 tiles)
  _Float16* Qsig = (_Float16*)(ws + 33554432);      // 16 MB  (row-major)
  _Float16* Zt = (_Float16*)(ws + 50331648);        // 32 MB  (4 x 512 tiles)
  _Float16* OutHead = (_Float16*)(ws + 83886080);   // 16 MB  (1024 tiles) -> 100,663,296 total

  // prep: x tiles + exp(wbias) tiles
  prep_tiles<<<1536, 256, 0, stream>>>(x, wb, x_h, ew_h);
  transpose_cast_w<<<dim3(32, 32, 4), 256, 0, stream>>>(Wq, Wk, Wv, Wo, WqkvT, WoT);

  // GEMM1: x @ [Wq|Wkv]; epilogue writes Qsig (row-major) and Zt (frag tiles)
  gemm_bt<0><<<dim3(64, 24, 1), 256, 0, stream>>>(x_h, WqkvT, Qsig, 16, 0, bq, bk, bv, nullptr,
                                                  Zt);

  // GEMM2: OutHead = q_sig * (ew@eKV)/(ew@eK), batched over b
  gemm_bt<3><<<dim3(16, 16, 4), 256, 0, stream>>>(ew_h, Zt, OutHead, 32, (long)4194304, nullptr,
                                                  nullptr, nullptr, Qsig, nullptr);

  // GEMM3: out = OutHead @ Wo + bo (fp32)
  gemm_bt<2><<<dim3(64, 8, 1), 256, 0, stream>>>(OutHead, WoT, d_out, 16, 0, bo, nullptr,
                                                 nullptr, nullptr, nullptr);
}

// Round 6
// 293.912 us; speedup vs baseline: 1.2868x; 1.0264x over previous
//
#include <hip/hip_runtime.h>
#include <hip/hip_bf16.h>

// AFT-Full on gfx950 — fragment-linear + coalesced-periphery edition.
// All GEMM operands live in global memory pre-swizzled into 128x64
// fragment-linear tiles (16 KB) matching MFMA 32x32x16 read order; staging
// global->LDS is an identity copy and every ds_read_b128 is lane-sequential
// (round-5 measured SQ_LDS_BANK_CONFLICT == 0).
// Round-6 changes: (1) weight tiler rebuilt around an LDS image ->
// coalesced f32 reads + contiguous 16-B tile stores (round-5 scatter cost
// ~12us); (2) Qsig stored in MFMA-C-tile order so GEMM1 writes and GEMM2
// reads are lane-contiguous 8B; (3) XCD-aware block swizzle in the GEMMs
// to keep Zt slices resident in one XCD's L2.
// Pipeline (4 launches): prep_all; GEMM1; GEMM2 (fused combine); GEMM3.

#define AS1(p) ((const __attribute__((address_space(1))) void*)(p))
#define AS3(p) ((__attribute__((address_space(3))) void*)(p))

typedef _Float16 half8 __attribute__((ext_vector_type(8)));
typedef _Float16 half4v __attribute__((ext_vector_type(4)));
typedef float floatx16 __attribute__((ext_vector_type(16)));

// Offset (in halfs) of element (r, k) inside a 128x64 fragment-linear tile.
// Layout: [ri=r>>5][ks=k>>4][khalf=(k>>3)&1][l32=r&31][j=k&7]  (8192 halfs).
__device__ __forceinline__ long frag_off(int r, int k) {
  return (long)(((((r >> 5) * 4 + (k >> 4)) * 2 + ((k >> 3) & 1)) * 32 + (r & 31)) * 8 + (k & 7));
}

// Qsig C-fragment-tile layout: value (t, ch) at
//   ((t>>5)*32 + (ch>>5))*1024 + ((t>>3)&3)*256 + (((t>>2)&1)*32 + (ch&31))*4 + (t&3)
// so a wave's half4v at (mt,q) is lane-contiguous:  base + q*256 + lane*4.

// ---------------- prep_all ----------------
// blocks [0,1024): x -> f16 frag tiles (64 tm x 16 tk, ld=1024)
// blocks [1024,1536): exp(wbias) -> f16 frag tiles (16 tm x 32 tk, ld=2048)
// blocks [1536,2048): W -> frag-linear B tiles via LDS (coalesced both ends)
__global__ __launch_bounds__(256) void prep_all(
    const float* __restrict__ x, const float* __restrict__ wb, const float* __restrict__ Wq,
    const float* __restrict__ Wk, const float* __restrict__ Wv, const float* __restrict__ Wo,
    _Float16* __restrict__ x_h, _Float16* __restrict__ ew_h, _Float16* __restrict__ WqkvT,
    _Float16* __restrict__ WoT) {
  __shared__ _Float16 lds[64 * 132];  // k-major, row stride 132 (bank-shift pad)
  const int bid = blockIdx.x;
  const int tid = threadIdx.x;

  if (bid < 1536) {
    const bool isx = bid < 1024;
    const float* src;
    _Float16* dst;
    int tm, tk, ld, trel;
    if (isx) {
      trel = bid; tm = bid >> 4; tk = bid & 15; src = x; dst = x_h; ld = 1024;
    } else {
      trel = bid - 1024; tm = trel >> 5; tk = trel & 31; src = wb; dst = ew_h; ld = 2048;
    }
    const long tbase = (long)trel * 8192;
#pragma unroll
    for (int p = 0; p < 4; ++p) {
      const int s = p * 256 + tid;  // tile slot (8 halfs)
      const int r = ((s >> 8) << 5) + (s & 31);
      const int k = ((s >> 6) & 3) * 16 + ((s >> 5) & 1) * 8;
      const float* sp = src + (long)(tm * 128 + r) * ld + tk * 64 + k;
      const float4 v0 = *(const float4*)sp;
      const float4 v1 = *(const float4*)(sp + 4);
      half8 h;
      if (isx) {
        h[0] = (_Float16)v0.x; h[1] = (_Float16)v0.y; h[2] = (_Float16)v0.z; h[3] = (_Float16)v0.w;
        h[4] = (_Float16)v1.x; h[5] = (_Float16)v1.y; h[6] = (_Float16)v1.z; h[7] = (_Float16)v1.w;
      } else {
        h[0] = (_Float16)__expf(v0.x); h[1] = (_Float16)__expf(v0.y);
        h[2] = (_Float16)__expf(v0.z); h[3] = (_Float16)__expf(v0.w);
        h[4] = (_Float16)__expf(v1.x); h[5] = (_Float16)__expf(v1.y);
        h[6] = (_Float16)__expf(v1.z); h[7] = (_Float16)__expf(v1.w);
      }
      *(half8*)(dst + tbase + (long)s * 8) = h;
    }
    return;
  }

  // ---- weight tiler ----
  // Output n-row mapping: Wq ch c -> jr=c; Wo -> jr=c;
  // Wk ch c -> jr=1024+(c>>5)*64+(c&31); Wv ch c -> +32. A 128-row KV tile tn
  // (8..23) holds channels [(tn-8)*64, +64) of BOTH Wk and Wv.
  const int b2 = bid - 1536;
  const float* src0;
  const float* src1 = nullptr;
  _Float16* dst;
  int tn, tk, cb = 0;
  if (b2 < 128) {
    tn = b2 >> 4; tk = b2 & 15; src0 = Wq; dst = WqkvT;
  } else if (b2 < 384) {
    const int t = b2 - 128;
    tn = 8 + (t >> 4); tk = t & 15; cb = (tn - 8) * 64; src0 = Wk; src1 = Wv; dst = WqkvT;
  } else {
    const int t = b2 - 384;
    tn = t >> 4; tk = t & 15; src0 = Wo; dst = WoT;
  }
  if (!src1) {  // plain: 64 k x 128 ch
#pragma unroll
    for (int p = 0; p < 8; ++p) {
      const int kl = p * 8 + (tid >> 5);
      const int cl = (tid & 31) * 4;
      const float4 v = *(const float4*)(src0 + (long)(tk * 64 + kl) * 1024 + tn * 128 + cl);
      half4v h;
      h[0] = (_Float16)v.x; h[1] = (_Float16)v.y; h[2] = (_Float16)v.z; h[3] = (_Float16)v.w;
      *(half4v*)(lds + kl * 132 + cl) = h;
    }
  } else {  // KV: two 64k x 64ch chunks -> interleaved rlocal image
#pragma unroll
    for (int m = 0; m < 2; ++m) {
      const float* s = m ? src1 : src0;
      const int rb = m ? 32 : 0;
#pragma unroll
      for (int p = 0; p < 4; ++p) {
        const int kl = p * 16 + (tid >> 4);
        const int cl = (tid & 15) * 4;
        const int rl = (cl >> 5) * 64 + rb + (cl & 31);
        const float4 v = *(const float4*)(s + (long)(tk * 64 + kl) * 1024 + cb + cl);
        half4v h;
        h[0] = (_Float16)v.x; h[1] = (_Float16)v.y; h[2] = (_Float16)v.z; h[3] = (_Float16)v.w;
        *(half4v*)(lds + kl * 132 + rl) = h;
      }
    }
  }
  __syncthreads();
  const long tbase = (long)(tn * 16 + tk) * 8192;
#pragma unroll
  for (int p = 0; p < 4; ++p) {
    const int s = p * 256 + tid;
    const int r = ((s >> 8) << 5) + (s & 31);
    const int kl = ((s >> 6) & 3) * 16 + ((s >> 5) & 1) * 8;
    half8 h;
#pragma unroll
    for (int j = 0; j < 8; ++j) h[j] = lds[(kl + j) * 132 + r];
    *(half8*)(dst + tbase + (long)s * 8) = h;
  }
}

// ---------------- main GEMM on fragment-linear tiles, MFMA 32x32x16, BK=64 ----------------
// MODE 0 (GEMM1): n0<1024 -> Qsig C-frag tiles sigmoid(+bq); else K/V pair ->
//   eK=exp(+bk), eKV=eK*(v+bv) -> Zt frag tiles (num j=g*64+l32, den +32).
// MODE 2 (GEMM3): fp32 row-major store + bias0.
// MODE 3 (GEMM2): num/den pair + Qsig(C-frag) -> OutHead frag tiles.
template <int MODE>
__global__ __launch_bounds__(256) void gemm_bt(
    const _Float16* __restrict__ A, const _Float16* __restrict__ Bt, void* __restrict__ Cv,
    int Ktiles, long batchB, const float* __restrict__ bias0, const float* __restrict__ bias1,
    const float* __restrict__ bias2, const _Float16* __restrict__ Qsig,
    _Float16* __restrict__ Zt) {
  __shared__ __align__(16) _Float16 sA[8192];
  __shared__ __align__(16) _Float16 sB[8192];
  const int tid = threadIdx.x;
  const int wave = tid >> 6, lane = tid & 63;
  const int l32 = lane & 31, khalf = lane >> 5;

  // XCD-aware swizzle: consecutive flat ids round-robin XCDs (f%8); remap so
  // each XCD owns a contiguous run of logical ids (shared Bt slices stay in
  // one XCD's L2).
  const int gx = gridDim.x, gy = gridDim.y;
  const int tot = gx * gy * gridDim.z;
  const int f = blockIdx.x + gx * (blockIdx.y + gy * blockIdx.z);
  const int nid = (f & 7) * (tot >> 3) + (f >> 3);
  const int bxs = nid % gx;
  const int bys = (nid / gx) % gy;
  const int bzs = nid / (gx * gy);

  const int m0 = bxs * 128, n0 = bys * 128;
  const int wm = (wave >> 1) * 64, wn = (wave & 1) * 64;

  const _Float16* Atile = A + (long)bxs * Ktiles * 8192;
  const _Float16* Btile = Bt + (long)bzs * batchB + (long)bys * Ktiles * 8192;

  floatx16 acc[2][2] = {};

  for (int tk = 0; tk < Ktiles; ++tk) {
    const _Float16* As = Atile + tk * 8192 + wave * 512 + lane * 8;
    const _Float16* Bs = Btile + tk * 8192 + wave * 512 + lane * 8;
#pragma unroll
    for (int c = 0; c < 4; ++c) {
      __builtin_amdgcn_global_load_lds(AS1(As + c * 2048), AS3(sA + c * 2048 + wave * 512), 16, 0, 0);
      __builtin_amdgcn_global_load_lds(AS1(Bs + c * 2048), AS3(sB + c * 2048 + wave * 512), 16, 0, 0);
    }
    __syncthreads();
#pragma unroll
    for (int ks = 0; ks < 4; ++ks) {
      half8 af[2], bf[2];
#pragma unroll
      for (int i = 0; i < 2; ++i) {
        af[i] = *(const half8*)(sA + (((wm >> 5) + i) * 4 + ks) * 512 + lane * 8);
        bf[i] = *(const half8*)(sB + (((wn >> 5) + i) * 4 + ks) * 512 + lane * 8);
      }
#pragma unroll
      for (int mt = 0; mt < 2; ++mt)
#pragma unroll
        for (int nt = 0; nt < 2; ++nt)
          acc[mt][nt] =
              __builtin_amdgcn_mfma_f32_32x32x16_f16(af[mt], bf[nt], acc[mt][nt], 0, 0, 0);
    }
    __syncthreads();
  }

  if (MODE == 0) {
    if (n0 < 1024) {
      _Float16* Qs = (_Float16*)Cv;
#pragma unroll
      for (int mt = 0; mt < 2; ++mt) {
        const long ttile = (m0 + wm + mt * 32) >> 5;
#pragma unroll
        for (int nt = 0; nt < 2; ++nt) {
          const int col = n0 + wn + nt * 32 + l32;
          const float bb = bias0[col];
          const long base = (ttile * 32 + (((n0 + wn) >> 5) + nt)) * 1024;
#pragma unroll
          for (int q = 0; q < 4; ++q) {
            half4v o;
#pragma unroll
            for (int rr = 0; rr < 4; ++rr) {
              const float v = acc[mt][nt][q * 4 + rr] + bb;
              o[rr] = (_Float16)(1.0f / (1.0f + __expf(-v)));
            }
            *(half4v*)(Qs + base + q * 256 + lane * 4) = o;
          }
        }
      }
    } else {
      const int g = (n0 - 1024 + wn) >> 6;  // 32-channel group
      const int ch = g * 32 + l32;
      const float bkc = bias1[ch], bvc = bias2[ch];
      const int jn = g * 64 + l32;  // num row in Zt; den = +32 (= +2048 halfs)
      const long tnbase = (long)(jn >> 7) * 32 * 8192;  // Zt Ktiles = 32
#pragma unroll
      for (int mt = 0; mt < 2; ++mt) {
#pragma unroll
        for (int q = 0; q < 4; ++q) {
          half4v numv, denv;
#pragma unroll
          for (int rr = 0; rr < 4; ++rr) {
            const float ek = __expf(acc[mt][0][q * 4 + rr] + bkc);
            const float vv = acc[mt][1][q * 4 + rr] + bvc;
            denv[rr] = (_Float16)ek;
            numv[rr] = (_Float16)(ek * vv);
          }
          const int row = m0 + wm + mt * 32 + 4 * khalf + 8 * q;  // +rr in vector
          const int b = row >> 11, s = row & 2047;
          const long off = (long)b * 4194304 + tnbase + (long)(s >> 6) * 8192 +
                           frag_off(jn & 127, s & 63);
          *(half4v*)(Zt + off) = numv;
          *(half4v*)(Zt + off + 2048) = denv;
        }
      }
    }
    return;
  }

  if (MODE == 3) {
    const int ch = ((n0 + wn) >> 6) * 32 + l32;
    _Float16* OH = (_Float16*)Cv;
#pragma unroll
    for (int mt = 0; mt < 2; ++mt) {
      const long ttile = (long)(bzs * 2048 + m0 + wm + mt * 32) >> 5;
      const long qbase = (ttile * 32 + ((n0 + wn) >> 6)) * 1024;
#pragma unroll
      for (int q = 0; q < 4; ++q) {
        const half4v qv = *(const half4v*)(Qsig + qbase + q * 256 + lane * 4);
#pragma unroll
        for (int rr = 0; rr < 4; ++rr) {
          const int reg = q * 4 + rr;
          const float num = acc[mt][0][reg], den = acc[mt][1][reg];
          const int r = m0 + wm + mt * 32 + 4 * khalf + 8 * q + rr;
          const int R = bzs * 2048 + r;  // global row for GEMM3's A
          const long off = ((long)(R >> 7) * 16 + (ch >> 6)) * 8192 + frag_off(R & 127, ch & 63);
          OH[off] = (_Float16)((float)qv[rr] * num / den);
        }
      }
    }
    return;
  }

  // MODE 2: fp32 row-major + bias0
#pragma unroll
  for (int mt = 0; mt < 2; ++mt)
#pragma unroll
    for (int nt = 0; nt < 2; ++nt) {
      const int col = n0 + wn + nt * 32 + l32;
      const float bb = bias0[col];
#pragma unroll
      for (int reg = 0; reg < 16; ++reg) {
        const int row = m0 + wm + mt * 32 + 4 * khalf + 8 * (reg >> 2) + (reg & 3);
        ((float*)Cv)[(long)row * 1024 + col] = acc[mt][nt][reg] + bb;
      }
    }
}

// ---------------- launch ----------------
extern "C" void kernel_launch(void* const* d_in, const int* in_sizes, int n_in, void* d_out,
                              int out_size, void* d_ws, size_t ws_size, hipStream_t stream) {
  const float* x = (const float*)d_in[0];
  const float* Wq = (const float*)d_in[1];
  const float* bq = (const float*)d_in[2];
  const float* Wk = (const float*)d_in[3];
  const float* bk = (const float*)d_in[4];
  const float* Wv = (const float*)d_in[5];
  const float* bv = (const float*)d_in[6];
  const float* Wo = (const float*)d_in[7];
  const float* bo = (const float*)d_in[8];
  const float* wb = (const float*)d_in[9];

  char* ws = (char*)d_ws;
  _Float16* x_h = (_Float16*)(ws + 0);              // 16 MB  (1024 frag tiles)
  _Float16* WqkvT = (_Float16*)(ws + 16777216);     //  6 MB  (384 frag tiles)
  _Float16* WoT = (_Float16*)(ws + 23068672);       //  2 MB  (128 frag tiles)
  _Float16* ew_h = (_Float16*)(ws + 25165824);      //  8 MB  (512 frag tiles)
  _Float16* Qsig = (_Float16*)(ws + 33554432);      // 16 MB  (C-frag tiles)
  _Float16* Zt = (_Float16*)(ws + 50331648);        // 32 MB  (4 x 512 frag tiles)
  _Float16* OutHead = (_Float16*)(ws + 83886080);   // 16 MB  (1024 frag tiles) -> 100,663,296

  // prep: x tiles + exp(wbias) tiles + weight tiles (one launch)
  prep_all<<<2048, 256, 0, stream>>>(x, wb, Wq, Wk, Wv, Wo, x_h, ew_h, WqkvT, WoT);

  // GEMM1: x @ [Wq|Wkv]; epilogue writes Qsig (C-frag) and Zt (frag tiles)
  gemm_bt<0><<<dim3(64, 24, 1), 256, 0, stream>>>(x_h, WqkvT, Qsig, 16, 0, bq, bk, bv, nullptr,
                                                  Zt);

  // GEMM2: OutHead = q_sig * (ew@eKV)/(ew@eK), batched over b
  gemm_bt<3><<<dim3(16, 16, 4), 256, 0, stream>>>(ew_h, Zt, OutHead, 32, (long)4194304, nullptr,
                                                  nullptr, nullptr, Qsig, nullptr);

  // GEMM3: out = OutHead @ Wo + bo (fp32)
  gemm_bt<2><<<dim3(64, 8, 1), 256, 0, stream>>>(OutHead, WoT, d_out, 16, 0, bo, nullptr,
                                                 nullptr, nullptr, nullptr);
}

// Round 7
// 272.934 us; speedup vs baseline: 1.3857x; 1.0769x over previous
//
#include <hip/hip_runtime.h>
#include <hip/hip_bf16.h>

// AFT-Full on gfx950 — fragment-linear + MX-fp8 GEMM2 edition.
// ew = exp(wbias) = 1 + E, |E|<=0.039 (rank-1 + small correction):
//   num = colsumZ + E@eKV, den = colsumK + E@eK.
// colsum* computed EXACTLY (f32 atomics in GEMM1 epilogue); the correction GEMM
// runs in fp8 e4m3 via mfma_scale_f32_32x32x64_f8f6f4 (scales pinned to 1.0;
// static scaling E*32, Z/4, undone /8 in epilogue). Quantization error of the
// correction term ~3e-5 relative — 30x below current f16 error, while direct
// fp8 of ew/Z would blow the 2.34e-3 threshold (cancellation analysis, r7).
// f16 GEMMs (GEMM1/GEMM3) unchanged: MFMA 32x32x16, 128x128 tile, BK=64,
// fragment-linear global tiles, identity staging, 0 bank conflicts.

#define AS1(p) ((const __attribute__((address_space(1))) void*)(p))
#define AS3(p) ((__attribute__((address_space(3))) void*)(p))

typedef _Float16 half8 __attribute__((ext_vector_type(8)));
typedef _Float16 half4v __attribute__((ext_vector_type(4)));
typedef float floatx16 __attribute__((ext_vector_type(16)));
typedef int intx4 __attribute__((ext_vector_type(4)));
typedef int intx8 __attribute__((ext_vector_type(8)));

// f16 fragment-linear 128x64 tile (8192 halfs): [r>>5][k>>4][(k>>3)&1][r&31][k&7]
__device__ __forceinline__ long frag_off(int r, int k) {
  return (long)(((((r >> 5) * 4 + (k >> 4)) * 2 + ((k >> 3) & 1)) * 32 + (r & 31)) * 8 + (k & 7));
}
// fp8 fragment-linear 128x128 tile (16384 B): [r>>5][ks=(k>>6)][u=(k>>4)&1][kh=(k>>5)&1][r&31][k&15]
// Lane (l32,kh) fragment for sub-block ks = two contiguous 16-B units (u=0/1):
// base = ri*4096 + ks*2048 + u*1024 + kh*512 + l32*16  -> identity staging, 0 conflicts.
__device__ __forceinline__ long off8(int r, int k) {
  return (long)((((((r >> 5) * 2 + ((k >> 6) & 1)) * 2 + ((k >> 4) & 1)) * 2 + ((k >> 5) & 1)) * 32 +
                 (r & 31)) * 16 + (k & 15));
}

// ---------------- prep_all ----------------
// blocks [0,1024): x -> f16 frag tiles (64 tm x 16 tk, ld=1024)
// blocks [1024,1536): W -> f16 frag-linear B tiles via LDS (KV channel-interleave)
// blocks [1536,1792): (exp(wbias)-1)*32 -> fp8 frag tiles (16 tt x 16 ts)
__global__ __launch_bounds__(256) void prep_all(
    const float* __restrict__ x, const float* __restrict__ wb, const float* __restrict__ Wq,
    const float* __restrict__ Wk, const float* __restrict__ Wv, const float* __restrict__ Wo,
    _Float16* __restrict__ x_h, char* __restrict__ E8, _Float16* __restrict__ WqkvT,
    _Float16* __restrict__ WoT) {
  __shared__ _Float16 lds[64 * 132];
  const int bid = blockIdx.x;
  const int tid = threadIdx.x;

  if (bid < 1024) {  // x -> f16 tiles
    const int tm = bid >> 4, tk = bid & 15;
    const long tbase = (long)bid * 8192;
#pragma unroll
    for (int p = 0; p < 4; ++p) {
      const int s = p * 256 + tid;
      const int r = ((s >> 8) << 5) + (s & 31);
      const int k = ((s >> 6) & 3) * 16 + ((s >> 5) & 1) * 8;
      const float* sp = x + (long)(tm * 128 + r) * 1024 + tk * 64 + k;
      const float4 v0 = *(const float4*)sp;
      const float4 v1 = *(const float4*)(sp + 4);
      half8 h;
      h[0] = (_Float16)v0.x; h[1] = (_Float16)v0.y; h[2] = (_Float16)v0.z; h[3] = (_Float16)v0.w;
      h[4] = (_Float16)v1.x; h[5] = (_Float16)v1.y; h[6] = (_Float16)v1.z; h[7] = (_Float16)v1.w;
      *(half8*)(x_h + tbase + (long)s * 8) = h;
    }
    return;
  }

  if (bid >= 1536) {  // E8: (exp(wb)-1)*32 -> fp8 frag tiles
    const int e = bid - 1536;
    const int tt = e >> 4, ts = e & 15;
    char* dst = E8 + (long)e * 16384;
#pragma unroll
    for (int p = 0; p < 16; ++p) {
      const int idx = p * 256 + tid;
      const int r = idx >> 5, k = (idx & 31) * 4;
      const float4 v = *(const float4*)(wb + (long)(tt * 128 + r) * 2048 + ts * 128 + k);
      const float e0 = (__expf(v.x) - 1.0f) * 32.0f, e1 = (__expf(v.y) - 1.0f) * 32.0f;
      const float e2 = (__expf(v.z) - 1.0f) * 32.0f, e3 = (__expf(v.w) - 1.0f) * 32.0f;
      int pk = __builtin_amdgcn_cvt_pk_fp8_f32(e0, e1, 0, false);
      pk = __builtin_amdgcn_cvt_pk_fp8_f32(e2, e3, pk, true);
      *(int*)(dst + off8(r, k)) = pk;
    }
    return;
  }

  // ---- weight tiler (f16) ----
  const int b2 = bid - 1024;
  const float* src0;
  const float* src1 = nullptr;
  _Float16* dst;
  int tn, tk, cb = 0;
  if (b2 < 128) {
    tn = b2 >> 4; tk = b2 & 15; src0 = Wq; dst = WqkvT;
  } else if (b2 < 384) {
    const int t = b2 - 128;
    tn = 8 + (t >> 4); tk = t & 15; cb = (tn - 8) * 64; src0 = Wk; src1 = Wv; dst = WqkvT;
  } else {
    const int t = b2 - 384;
    tn = t >> 4; tk = t & 15; src0 = Wo; dst = WoT;
  }
  if (!src1) {
#pragma unroll
    for (int p = 0; p < 8; ++p) {
      const int kl = p * 8 + (tid >> 5);
      const int cl = (tid & 31) * 4;
      const float4 v = *(const float4*)(src0 + (long)(tk * 64 + kl) * 1024 + tn * 128 + cl);
      half4v h;
      h[0] = (_Float16)v.x; h[1] = (_Float16)v.y; h[2] = (_Float16)v.z; h[3] = (_Float16)v.w;
      *(half4v*)(lds + kl * 132 + cl) = h;
    }
  } else {
#pragma unroll
    for (int m = 0; m < 2; ++m) {
      const float* s = m ? src1 : src0;
      const int rb = m ? 32 : 0;
#pragma unroll
      for (int p = 0; p < 4; ++p) {
        const int kl = p * 16 + (tid >> 4);
        const int cl = (tid & 15) * 4;
        const int rl = (cl >> 5) * 64 + rb + (cl & 31);
        const float4 v = *(const float4*)(s + (long)(tk * 64 + kl) * 1024 + cb + cl);
        half4v h;
        h[0] = (_Float16)v.x; h[1] = (_Float16)v.y; h[2] = (_Float16)v.z; h[3] = (_Float16)v.w;
        *(half4v*)(lds + kl * 132 + rl) = h;
      }
    }
  }
  __syncthreads();
  const long tbase = (long)(tn * 16 + tk) * 8192;
#pragma unroll
  for (int p = 0; p < 4; ++p) {
    const int s = p * 256 + tid;
    const int r = ((s >> 8) << 5) + (s & 31);
    const int kl = ((s >> 6) & 3) * 16 + ((s >> 5) & 1) * 8;
    half8 h;
#pragma unroll
    for (int j = 0; j < 8; ++j) h[j] = lds[(kl + j) * 132 + r];
    *(half8*)(dst + tbase + (long)s * 8) = h;
  }
}

// ---------------- f16 GEMM (fragment-linear tiles), MFMA 32x32x16, BK=64 ----------------
// MODE 0 (GEMM1): n0<1024 -> Qsig C-frag tiles sigmoid(+bq); else K/V pair:
//   eK=exp(+bk), eKV=eK*(v+bv) -> Zt8 fp8 (/4) + f32 colsum atomics (csZ,csK).
// MODE 2 (GEMM3): fp32 row-major store + bias0.
template <int MODE>
__global__ __launch_bounds__(256) void gemm_bt(
    const _Float16* __restrict__ A, const _Float16* __restrict__ Bt, void* __restrict__ Cv,
    int Ktiles, const float* __restrict__ bias0, const float* __restrict__ bias1,
    const float* __restrict__ bias2, char* __restrict__ Zt8, float* __restrict__ cs) {
  __shared__ __align__(16) _Float16 sA[8192];
  __shared__ __align__(16) _Float16 sB[8192];
  const int tid = threadIdx.x;
  const int wave = tid >> 6, lane = tid & 63;
  const int l32 = lane & 31, khalf = lane >> 5;

  const int gx = gridDim.x;
  const int tot = gx * gridDim.y;
  const int f = blockIdx.x + gx * blockIdx.y;
  const int nid = (f & 7) * (tot >> 3) + (f >> 3);
  const int bxs = nid % gx, bys = nid / gx;

  const int m0 = bxs * 128, n0 = bys * 128;
  const int wm = (wave >> 1) * 64, wn = (wave & 1) * 64;

  const _Float16* Atile = A + (long)bxs * Ktiles * 8192;
  const _Float16* Btile = Bt + (long)bys * Ktiles * 8192;

  floatx16 acc[2][2] = {};

  for (int tk = 0; tk < Ktiles; ++tk) {
    const _Float16* As = Atile + tk * 8192 + wave * 512 + lane * 8;
    const _Float16* Bs = Btile + tk * 8192 + wave * 512 + lane * 8;
#pragma unroll
    for (int c = 0; c < 4; ++c) {
      __builtin_amdgcn_global_load_lds(AS1(As + c * 2048), AS3(sA + c * 2048 + wave * 512), 16, 0, 0);
      __builtin_amdgcn_global_load_lds(AS1(Bs + c * 2048), AS3(sB + c * 2048 + wave * 512), 16, 0, 0);
    }
    __syncthreads();
#pragma unroll
    for (int ks = 0; ks < 4; ++ks) {
      half8 af[2], bf[2];
#pragma unroll
      for (int i = 0; i < 2; ++i) {
        af[i] = *(const half8*)(sA + (((wm >> 5) + i) * 4 + ks) * 512 + lane * 8);
        bf[i] = *(const half8*)(sB + (((wn >> 5) + i) * 4 + ks) * 512 + lane * 8);
      }
#pragma unroll
      for (int mt = 0; mt < 2; ++mt)
#pragma unroll
        for (int nt = 0; nt < 2; ++nt)
          acc[mt][nt] =
              __builtin_amdgcn_mfma_f32_32x32x16_f16(af[mt], bf[nt], acc[mt][nt], 0, 0, 0);
    }
    __syncthreads();
  }

  if (MODE == 0) {
    if (n0 < 1024) {
      _Float16* Qs = (_Float16*)Cv;
#pragma unroll
      for (int mt = 0; mt < 2; ++mt) {
        const long ttile = (m0 + wm + mt * 32) >> 5;
#pragma unroll
        for (int nt = 0; nt < 2; ++nt) {
          const int col = n0 + wn + nt * 32 + l32;
          const float bb = bias0[col];
          const long base = (ttile * 32 + (((n0 + wn) >> 5) + nt)) * 1024;
#pragma unroll
          for (int q = 0; q < 4; ++q) {
            half4v o;
#pragma unroll
            for (int rr = 0; rr < 4; ++rr) {
              const float v = acc[mt][nt][q * 4 + rr] + bb;
              o[rr] = (_Float16)(1.0f / (1.0f + __expf(-v)));
            }
            *(half4v*)(Qs + base + q * 256 + lane * 4) = o;
          }
        }
      }
    } else {
      const int g = (n0 - 1024 + wn) >> 6;  // 32-channel group
      const int ch = g * 32 + l32;
      const float bkc = bias1[ch], bvc = bias2[ch];
      const int jn = g * 64 + l32;          // Zt num row; den = +32 (same 128-tile)
      const int b = m0 >> 11;
      char* Z8 = Zt8 + (long)b * 4194304 +
                 ((long)(jn >> 7) * 16 + ((m0 & 2047) >> 7)) * 16384;
      const int jnl = jn & 127;
      float sk = 0.f, sz = 0.f;
#pragma unroll
      for (int mt = 0; mt < 2; ++mt) {
#pragma unroll
        for (int q = 0; q < 4; ++q) {
          float ekv[4], ekk[4];
#pragma unroll
          for (int rr = 0; rr < 4; ++rr) {
            const float ek = __expf(acc[mt][0][q * 4 + rr] + bkc);
            const float vv = acc[mt][1][q * 4 + rr] + bvc;
            ekk[rr] = ek;
            ekv[rr] = ek * vv;
            sk += ek;
            sz += ek * vv;
          }
          const int sl = wm + mt * 32 + 4 * khalf + 8 * q;  // s within tile (+rr)
          int pn = __builtin_amdgcn_cvt_pk_fp8_f32(ekv[0] * 0.25f, ekv[1] * 0.25f, 0, false);
          pn = __builtin_amdgcn_cvt_pk_fp8_f32(ekv[2] * 0.25f, ekv[3] * 0.25f, pn, true);
          int pd = __builtin_amdgcn_cvt_pk_fp8_f32(ekk[0] * 0.25f, ekk[1] * 0.25f, 0, false);
          pd = __builtin_amdgcn_cvt_pk_fp8_f32(ekk[2] * 0.25f, ekk[3] * 0.25f, pd, true);
          *(int*)(Z8 + off8(jnl, sl)) = pn;
          *(int*)(Z8 + off8(jnl + 32, sl)) = pd;
        }
      }
      atomicAdd(&cs[(long)b * 2048 + ch * 2], sz);
      atomicAdd(&cs[(long)b * 2048 + ch * 2 + 1], sk);
    }
    return;
  }

  // MODE 2: fp32 row-major + bias0
#pragma unroll
  for (int mt = 0; mt < 2; ++mt)
#pragma unroll
    for (int nt = 0; nt < 2; ++nt) {
      const int col = n0 + wn + nt * 32 + l32;
      const float bb = bias0[col];
#pragma unroll
      for (int reg = 0; reg < 16; ++reg) {
        const int row = m0 + wm + mt * 32 + 4 * khalf + 8 * (reg >> 2) + (reg & 3);
        ((float*)Cv)[(long)row * 1024 + col] = acc[mt][nt][reg] + bb;
      }
    }
}

// ---------------- GEMM2: fp8 correction  acc = (E*32) @ (Z/4)^T, BK=128 ----------------
// OutHead = Qsig * (csZ + accn/8) / (csK + accd/8), grid (16,16,4).
__global__ __launch_bounds__(256) void gemm2_fp8(
    const char* __restrict__ E8, const char* __restrict__ Zt8, _Float16* __restrict__ OH,
    const _Float16* __restrict__ Qsig, const float* __restrict__ cs) {
  __shared__ __align__(16) char sA[16384];
  __shared__ __align__(16) char sB[16384];
  const int tid = threadIdx.x;
  const int wave = tid >> 6, lane = tid & 63;
  const int l32 = lane & 31, khalf = lane >> 5;

  const int f = blockIdx.x + 16 * (blockIdx.y + 16 * blockIdx.z);
  const int nid = (f & 7) * 128 + (f >> 3);
  const int bxs = nid & 15, bys = (nid >> 4) & 15, bzs = nid >> 8;

  const int m0 = bxs * 128, n0 = bys * 128;
  const int wm = (wave >> 1) * 64, wn = (wave & 1) * 64;

  const char* At = E8 + (long)bxs * 16 * 16384;
  const char* Bt = Zt8 + (long)bzs * 4194304 + (long)bys * 16 * 16384;

  floatx16 acc[2][2] = {};

  for (int tk = 0; tk < 16; ++tk) {
    const char* As = At + tk * 16384 + wave * 1024 + lane * 16;
    const char* Bs = Bt + tk * 16384 + wave * 1024 + lane * 16;
#pragma unroll
    for (int c = 0; c < 4; ++c) {
      __builtin_amdgcn_global_load_lds(AS1(As + c * 4096), AS3(sA + c * 4096 + wave * 1024), 16, 0, 0);
      __builtin_amdgcn_global_load_lds(AS1(Bs + c * 4096), AS3(sB + c * 4096 + wave * 1024), 16, 0, 0);
    }
    __syncthreads();
#pragma unroll
    for (int ks = 0; ks < 2; ++ks) {
      intx8 a8[2], b8[2];
#pragma unroll
      for (int i = 0; i < 2; ++i) {
        const char* pa = sA + (((wm >> 5) + i) * 2 + ks) * 2048 + khalf * 512 + l32 * 16;
        const intx4 alo = *(const intx4*)pa;
        const intx4 ahi = *(const intx4*)(pa + 1024);
        a8[i] = __builtin_shufflevector(alo, ahi, 0, 1, 2, 3, 4, 5, 6, 7);
        const char* pb = sB + (((wn >> 5) + i) * 2 + ks) * 2048 + khalf * 512 + l32 * 16;
        const intx4 blo = *(const intx4*)pb;
        const intx4 bhi = *(const intx4*)(pb + 1024);
        b8[i] = __builtin_shufflevector(blo, bhi, 0, 1, 2, 3, 4, 5, 6, 7);
      }
#pragma unroll
      for (int mt = 0; mt < 2; ++mt)
#pragma unroll
        for (int nt = 0; nt < 2; ++nt)
          acc[mt][nt] = __builtin_amdgcn_mfma_scale_f32_32x32x64_f8f6f4(
              a8[mt], b8[nt], acc[mt][nt], 0, 0, 0, 127u, 0, 127u);
    }
    __syncthreads();
  }

  const int ch = ((n0 + wn) >> 6) * 32 + l32;
  const float2 c2 = *(const float2*)(cs + (long)bzs * 2048 + ch * 2);  // (csZ, csK)
#pragma unroll
  for (int mt = 0; mt < 2; ++mt) {
    const long ttile = (long)(bzs * 2048 + m0 + wm + mt * 32) >> 5;
    const long qbase = (ttile * 32 + ((n0 + wn) >> 6)) * 1024;
#pragma unroll
    for (int q = 0; q < 4; ++q) {
      const half4v qv = *(const half4v*)(Qsig + qbase + q * 256 + lane * 4);
#pragma unroll
      for (int rr = 0; rr < 4; ++rr) {
        const int reg = q * 4 + rr;
        const float num = c2.x + acc[mt][0][reg] * 0.125f;
        const float den = c2.y + acc[mt][1][reg] * 0.125f;
        const int r = m0 + wm + mt * 32 + 4 * khalf + 8 * q + rr;
        const int R = bzs * 2048 + r;
        const long off = ((long)(R >> 7) * 16 + (ch >> 6)) * 8192 + frag_off(R & 127, ch & 63);
        OH[off] = (_Float16)((float)qv[rr] * num / den);
      }
    }
  }
}

// ---------------- launch ----------------
extern "C" void kernel_launch(void* const* d_in, const int* in_sizes, int n_in, void* d_out,
                              int out_size, void* d_ws, size_t ws_size, hipStream_t stream) {
  const float* x = (const float*)d_in[0];
  const float* Wq = (const float*)d_in[1];
  const float* bq = (const float*)d_in[2];
  const float* Wk = (const float*)d_in[3];
  const float* bk = (const float*)d_in[4];
  const float* Wv = (const float*)d_in[5];
  const float* bv = (const float*)d_in[6];
  const float* Wo = (const float*)d_in[7];
  const float* bo = (const float*)d_in[8];
  const float* wb = (const float*)d_in[9];

  char* ws = (char*)d_ws;
  _Float16* x_h = (_Float16*)(ws + 0);              // 16 MB  (1024 f16 frag tiles)
  _Float16* WqkvT = (_Float16*)(ws + 16777216);     //  6 MB
  _Float16* WoT = (_Float16*)(ws + 23068672);       //  2 MB
  char* E8 = (char*)(ws + 25165824);                //  4 MB  (256 fp8 frag tiles)
  _Float16* Qsig = (_Float16*)(ws + 29360128);      // 16 MB  (C-frag tiles)
  char* Zt8 = (char*)(ws + 46137344);               // 16 MB  (fp8 frag tiles, 4 batches)
  _Float16* OutHead = (_Float16*)(ws + 62914560);   // 16 MB  (f16 frag tiles)
  float* cs = (float*)(ws + 79691776);              // 32 KB  (csZ,csK interleaved) -> ~79.7 MB

  hipMemsetAsync(cs, 0, 4 * 2048 * sizeof(float), stream);

  // prep: x tiles + weight tiles + E8 tiles
  prep_all<<<1792, 256, 0, stream>>>(x, wb, Wq, Wk, Wv, Wo, x_h, E8, WqkvT, WoT);

  // GEMM1: x @ [Wq|Wkv]; epilogue -> Qsig (C-frag), Zt8 (fp8), colsum atomics
  gemm_bt<0><<<dim3(64, 24), 256, 0, stream>>>(x_h, WqkvT, Qsig, 16, bq, bk, bv, Zt8, cs);

  // GEMM2 (fp8 correction + rank-1): OutHead = Qsig*(csZ+E@Z)/(csK+E@eK)
  gemm2_fp8<<<dim3(16, 16, 4), 256, 0, stream>>>(E8, Zt8, OutHead, Qsig, cs);

  // GEMM3: out = OutHead @ Wo + bo (fp32)
  gemm_bt<2><<<dim3(64, 8), 256, 0, stream>>>(OutHead, WoT, d_out, 16, bo, nullptr, nullptr,
                                              nullptr, nullptr);
}

// Round 8
// 262.098 us; speedup vs baseline: 1.4430x; 1.0413x over previous
//
#include <hip/hip_runtime.h>
#include <hip/hip_bf16.h>

// AFT-Full on gfx950 — fragment-linear + MX-fp8 GEMM2 + XCD-slab scheduling.
// ew = exp(wbias) = 1 + E, |E|<=0.039: num = colsumZ + E@eKV, den = colsumK + E@eK.
// colsums exact (f32 atomics in GEMM1 epilogue); correction GEMM in fp8 e4m3 via
// mfma_scale_f32_32x32x64_f8f6f4 (scales pinned 1.0; static E*32, Z/4, /8 undo).
// Round-8: GEMM1/GEMM3 block-order remap gives each XCD one contiguous m-slab
// (8 m-tiles) walked n-slowly -> A-slab stays L2-resident, B fetched once/XCD
// (round-7 measured GEMM1 FETCH 200 MB vs 22 MB working set, 9x thrash).

#define AS1(p) ((const __attribute__((address_space(1))) void*)(p))
#define AS3(p) ((__attribute__((address_space(3))) void*)(p))

typedef _Float16 half8 __attribute__((ext_vector_type(8)));
typedef _Float16 half4v __attribute__((ext_vector_type(4)));
typedef float floatx16 __attribute__((ext_vector_type(16)));
typedef int intx4 __attribute__((ext_vector_type(4)));
typedef int intx8 __attribute__((ext_vector_type(8)));

// f16 fragment-linear 128x64 tile (8192 halfs): [r>>5][k>>4][(k>>3)&1][r&31][k&7]
__device__ __forceinline__ long frag_off(int r, int k) {
  return (long)(((((r >> 5) * 4 + (k >> 4)) * 2 + ((k >> 3) & 1)) * 32 + (r & 31)) * 8 + (k & 7));
}
// fp8 fragment-linear 128x128 tile (16384 B)
__device__ __forceinline__ long off8(int r, int k) {
  return (long)((((((r >> 5) * 2 + ((k >> 6) & 1)) * 2 + ((k >> 4) & 1)) * 2 + ((k >> 5) & 1)) * 32 +
                 (r & 31)) * 16 + (k & 15));
}

// ---------------- prep_all ----------------
// blocks [0,1024): x -> f16 frag tiles; [1024,1536): W -> f16 tiles via LDS;
// [1536,1792): (exp(wbias)-1)*32 -> fp8 frag tiles
__global__ __launch_bounds__(256) void prep_all(
    const float* __restrict__ x, const float* __restrict__ wb, const float* __restrict__ Wq,
    const float* __restrict__ Wk, const float* __restrict__ Wv, const float* __restrict__ Wo,
    _Float16* __restrict__ x_h, char* __restrict__ E8, _Float16* __restrict__ WqkvT,
    _Float16* __restrict__ WoT) {
  __shared__ _Float16 lds[64 * 132];
  const int bid = blockIdx.x;
  const int tid = threadIdx.x;

  if (bid < 1024) {  // x -> f16 tiles
    const int tm = bid >> 4, tk = bid & 15;
    const long tbase = (long)bid * 8192;
#pragma unroll
    for (int p = 0; p < 4; ++p) {
      const int s = p * 256 + tid;
      const int r = ((s >> 8) << 5) + (s & 31);
      const int k = ((s >> 6) & 3) * 16 + ((s >> 5) & 1) * 8;
      const float* sp = x + (long)(tm * 128 + r) * 1024 + tk * 64 + k;
      const float4 v0 = *(const float4*)sp;
      const float4 v1 = *(const float4*)(sp + 4);
      half8 h;
      h[0] = (_Float16)v0.x; h[1] = (_Float16)v0.y; h[2] = (_Float16)v0.z; h[3] = (_Float16)v0.w;
      h[4] = (_Float16)v1.x; h[5] = (_Float16)v1.y; h[6] = (_Float16)v1.z; h[7] = (_Float16)v1.w;
      *(half8*)(x_h + tbase + (long)s * 8) = h;
    }
    return;
  }

  if (bid >= 1536) {  // E8: (exp(wb)-1)*32 -> fp8 frag tiles
    const int e = bid - 1536;
    const int tt = e >> 4, ts = e & 15;
    char* dst = E8 + (long)e * 16384;
#pragma unroll
    for (int p = 0; p < 16; ++p) {
      const int idx = p * 256 + tid;
      const int r = idx >> 5, k = (idx & 31) * 4;
      const float4 v = *(const float4*)(wb + (long)(tt * 128 + r) * 2048 + ts * 128 + k);
      const float e0 = (__expf(v.x) - 1.0f) * 32.0f, e1 = (__expf(v.y) - 1.0f) * 32.0f;
      const float e2 = (__expf(v.z) - 1.0f) * 32.0f, e3 = (__expf(v.w) - 1.0f) * 32.0f;
      int pk = __builtin_amdgcn_cvt_pk_fp8_f32(e0, e1, 0, false);
      pk = __builtin_amdgcn_cvt_pk_fp8_f32(e2, e3, pk, true);
      *(int*)(dst + off8(r, k)) = pk;
    }
    return;
  }

  // ---- weight tiler (f16) ----
  const int b2 = bid - 1024;
  const float* src0;
  const float* src1 = nullptr;
  _Float16* dst;
  int tn, tk, cb = 0;
  if (b2 < 128) {
    tn = b2 >> 4; tk = b2 & 15; src0 = Wq; dst = WqkvT;
  } else if (b2 < 384) {
    const int t = b2 - 128;
    tn = 8 + (t >> 4); tk = t & 15; cb = (tn - 8) * 64; src0 = Wk; src1 = Wv; dst = WqkvT;
  } else {
    const int t = b2 - 384;
    tn = t >> 4; tk = t & 15; src0 = Wo; dst = WoT;
  }
  if (!src1) {
#pragma unroll
    for (int p = 0; p < 8; ++p) {
      const int kl = p * 8 + (tid >> 5);
      const int cl = (tid & 31) * 4;
      const float4 v = *(const float4*)(src0 + (long)(tk * 64 + kl) * 1024 + tn * 128 + cl);
      half4v h;
      h[0] = (_Float16)v.x; h[1] = (_Float16)v.y; h[2] = (_Float16)v.z; h[3] = (_Float16)v.w;
      *(half4v*)(lds + kl * 132 + cl) = h;
    }
  } else {
#pragma unroll
    for (int m = 0; m < 2; ++m) {
      const float* s = m ? src1 : src0;
      const int rb = m ? 32 : 0;
#pragma unroll
      for (int p = 0; p < 4; ++p) {
        const int kl = p * 16 + (tid >> 4);
        const int cl = (tid & 15) * 4;
        const int rl = (cl >> 5) * 64 + rb + (cl & 31);
        const float4 v = *(const float4*)(s + (long)(tk * 64 + kl) * 1024 + cb + cl);
        half4v h;
        h[0] = (_Float16)v.x; h[1] = (_Float16)v.y; h[2] = (_Float16)v.z; h[3] = (_Float16)v.w;
        *(half4v*)(lds + kl * 132 + rl) = h;
      }
    }
  }
  __syncthreads();
  const long tbase = (long)(tn * 16 + tk) * 8192;
#pragma unroll
  for (int p = 0; p < 4; ++p) {
    const int s = p * 256 + tid;
    const int r = ((s >> 8) << 5) + (s & 31);
    const int kl = ((s >> 6) & 3) * 16 + ((s >> 5) & 1) * 8;
    half8 h;
#pragma unroll
    for (int j = 0; j < 8; ++j) h[j] = lds[(kl + j) * 132 + r];
    *(half8*)(dst + tbase + (long)s * 8) = h;
  }
}

// ---------------- f16 GEMM (fragment-linear tiles), MFMA 32x32x16, BK=64 ----------------
// Block-order: XCD x (hw id f, x=f&7) owns m-slab bxs in [8x,8x+8), walks n slowly:
//   bxs=(f&7)*8+((f>>3)&7), bys=f>>6.   (requires gridDim.x==64)
// MODE 0 (GEMM1): n0<1024 -> Qsig C-frag sigmoid(+bq); else K/V pair ->
//   eK=exp(+bk), eKV=eK*(v+bv) -> Zt8 fp8 (/4) + f32 colsum atomics.
// MODE 2 (GEMM3): fp32 row-major store + bias0.
template <int MODE>
__global__ __launch_bounds__(256) void gemm_bt(
    const _Float16* __restrict__ A, const _Float16* __restrict__ Bt, void* __restrict__ Cv,
    int Ktiles, const float* __restrict__ bias0, const float* __restrict__ bias1,
    const float* __restrict__ bias2, char* __restrict__ Zt8, float* __restrict__ cs) {
  __shared__ __align__(16) _Float16 sA[8192];
  __shared__ __align__(16) _Float16 sB[8192];
  const int tid = threadIdx.x;
  const int wave = tid >> 6, lane = tid & 63;
  const int l32 = lane & 31, khalf = lane >> 5;

  const int f = blockIdx.x + 64 * blockIdx.y;
  const int bxs = (f & 7) * 8 + ((f >> 3) & 7);
  const int bys = f >> 6;

  const int m0 = bxs * 128, n0 = bys * 128;
  const int wm = (wave >> 1) * 64, wn = (wave & 1) * 64;

  const _Float16* Atile = A + (long)bxs * Ktiles * 8192;
  const _Float16* Btile = Bt + (long)bys * Ktiles * 8192;

  floatx16 acc[2][2] = {};

  for (int tk = 0; tk < Ktiles; ++tk) {
    const _Float16* As = Atile + tk * 8192 + wave * 512 + lane * 8;
    const _Float16* Bs = Btile + tk * 8192 + wave * 512 + lane * 8;
#pragma unroll
    for (int c = 0; c < 4; ++c) {
      __builtin_amdgcn_global_load_lds(AS1(As + c * 2048), AS3(sA + c * 2048 + wave * 512), 16, 0, 0);
      __builtin_amdgcn_global_load_lds(AS1(Bs + c * 2048), AS3(sB + c * 2048 + wave * 512), 16, 0, 0);
    }
    __syncthreads();
#pragma unroll
    for (int ks = 0; ks < 4; ++ks) {
      half8 af[2], bf[2];
#pragma unroll
      for (int i = 0; i < 2; ++i) {
        af[i] = *(const half8*)(sA + (((wm >> 5) + i) * 4 + ks) * 512 + lane * 8);
        bf[i] = *(const half8*)(sB + (((wn >> 5) + i) * 4 + ks) * 512 + lane * 8);
      }
#pragma unroll
      for (int mt = 0; mt < 2; ++mt)
#pragma unroll
        for (int nt = 0; nt < 2; ++nt)
          acc[mt][nt] =
              __builtin_amdgcn_mfma_f32_32x32x16_f16(af[mt], bf[nt], acc[mt][nt], 0, 0, 0);
    }
    __syncthreads();
  }

  if (MODE == 0) {
    if (n0 < 1024) {
      _Float16* Qs = (_Float16*)Cv;
#pragma unroll
      for (int mt = 0; mt < 2; ++mt) {
        const long ttile = (m0 + wm + mt * 32) >> 5;
#pragma unroll
        for (int nt = 0; nt < 2; ++nt) {
          const int col = n0 + wn + nt * 32 + l32;
          const float bb = bias0[col];
          const long base = (ttile * 32 + (((n0 + wn) >> 5) + nt)) * 1024;
#pragma unroll
          for (int q = 0; q < 4; ++q) {
            half4v o;
#pragma unroll
            for (int rr = 0; rr < 4; ++rr) {
              const float v = acc[mt][nt][q * 4 + rr] + bb;
              o[rr] = (_Float16)(1.0f / (1.0f + __expf(-v)));
            }
            *(half4v*)(Qs + base + q * 256 + lane * 4) = o;
          }
        }
      }
    } else {
      const int g = (n0 - 1024 + wn) >> 6;  // 32-channel group
      const int ch = g * 32 + l32;
      const float bkc = bias1[ch], bvc = bias2[ch];
      const int jn = g * 64 + l32;          // Zt num row; den = +32 (same 128-tile)
      const int b = m0 >> 11;
      char* Z8 = Zt8 + (long)b * 4194304 +
                 ((long)(jn >> 7) * 16 + ((m0 & 2047) >> 7)) * 16384;
      const int jnl = jn & 127;
      float sk = 0.f, sz = 0.f;
#pragma unroll
      for (int mt = 0; mt < 2; ++mt) {
#pragma unroll
        for (int q = 0; q < 4; ++q) {
          float ekv[4], ekk[4];
#pragma unroll
          for (int rr = 0; rr < 4; ++rr) {
            const float ek = __expf(acc[mt][0][q * 4 + rr] + bkc);
            const float vv = acc[mt][1][q * 4 + rr] + bvc;
            ekk[rr] = ek;
            ekv[rr] = ek * vv;
            sk += ek;
            sz += ek * vv;
          }
          const int sl = wm + mt * 32 + 4 * khalf + 8 * q;  // s within tile (+rr)
          int pn = __builtin_amdgcn_cvt_pk_fp8_f32(ekv[0] * 0.25f, ekv[1] * 0.25f, 0, false);
          pn = __builtin_amdgcn_cvt_pk_fp8_f32(ekv[2] * 0.25f, ekv[3] * 0.25f, pn, true);
          int pd = __builtin_amdgcn_cvt_pk_fp8_f32(ekk[0] * 0.25f, ekk[1] * 0.25f, 0, false);
          pd = __builtin_amdgcn_cvt_pk_fp8_f32(ekk[2] * 0.25f, ekk[3] * 0.25f, pd, true);
          *(int*)(Z8 + off8(jnl, sl)) = pn;
          *(int*)(Z8 + off8(jnl + 32, sl)) = pd;
        }
      }
      atomicAdd(&cs[(long)b * 2048 + ch * 2], sz);
      atomicAdd(&cs[(long)b * 2048 + ch * 2 + 1], sk);
    }
    return;
  }

  // MODE 2: fp32 row-major + bias0
#pragma unroll
  for (int mt = 0; mt < 2; ++mt)
#pragma unroll
    for (int nt = 0; nt < 2; ++nt) {
      const int col = n0 + wn + nt * 32 + l32;
      const float bb = bias0[col];
#pragma unroll
      for (int reg = 0; reg < 16; ++reg) {
        const int row = m0 + wm + mt * 32 + 4 * khalf + 8 * (reg >> 2) + (reg & 3);
        ((float*)Cv)[(long)row * 1024 + col] = acc[mt][nt][reg] + bb;
      }
    }
}

// ---------------- GEMM2: fp8 correction  acc = (E*32) @ (Z/4)^T, BK=128 ----------------
// OutHead = Qsig * (csZ + accn/8) / (csK + accd/8), grid (16,16,4).
__global__ __launch_bounds__(256) void gemm2_fp8(
    const char* __restrict__ E8, const char* __restrict__ Zt8, _Float16* __restrict__ OH,
    const _Float16* __restrict__ Qsig, const float* __restrict__ cs) {
  __shared__ __align__(16) char sA[16384];
  __shared__ __align__(16) char sB[16384];
  const int tid = threadIdx.x;
  const int wave = tid >> 6, lane = tid & 63;
  const int l32 = lane & 31, khalf = lane >> 5;

  const int f = blockIdx.x + 16 * (blockIdx.y + 16 * blockIdx.z);
  const int nid = (f & 7) * 128 + (f >> 3);
  const int bxs = nid & 15, bys = (nid >> 4) & 15, bzs = nid >> 8;

  const int m0 = bxs * 128, n0 = bys * 128;
  const int wm = (wave >> 1) * 64, wn = (wave & 1) * 64;

  const char* At = E8 + (long)bxs * 16 * 16384;
  const char* Bt = Zt8 + (long)bzs * 4194304 + (long)bys * 16 * 16384;

  floatx16 acc[2][2] = {};

  for (int tk = 0; tk < 16; ++tk) {
    const char* As = At + tk * 16384 + wave * 1024 + lane * 16;
    const char* Bs = Bt + tk * 16384 + wave * 1024 + lane * 16;
#pragma unroll
    for (int c = 0; c < 4; ++c) {
      __builtin_amdgcn_global_load_lds(AS1(As + c * 4096), AS3(sA + c * 4096 + wave * 1024), 16, 0, 0);
      __builtin_amdgcn_global_load_lds(AS1(Bs + c * 4096), AS3(sB + c * 4096 + wave * 1024), 16, 0, 0);
    }
    __syncthreads();
#pragma unroll
    for (int ks = 0; ks < 2; ++ks) {
      intx8 a8[2], b8[2];
#pragma unroll
      for (int i = 0; i < 2; ++i) {
        const char* pa = sA + (((wm >> 5) + i) * 2 + ks) * 2048 + khalf * 512 + l32 * 16;
        const intx4 alo = *(const intx4*)pa;
        const intx4 ahi = *(const intx4*)(pa + 1024);
        a8[i] = __builtin_shufflevector(alo, ahi, 0, 1, 2, 3, 4, 5, 6, 7);
        const char* pb = sB + (((wn >> 5) + i) * 2 + ks) * 2048 + khalf * 512 + l32 * 16;
        const intx4 blo = *(const intx4*)pb;
        const intx4 bhi = *(const intx4*)(pb + 1024);
        b8[i] = __builtin_shufflevector(blo, bhi, 0, 1, 2, 3, 4, 5, 6, 7);
      }
#pragma unroll
      for (int mt = 0; mt < 2; ++mt)
#pragma unroll
        for (int nt = 0; nt < 2; ++nt)
          acc[mt][nt] = __builtin_amdgcn_mfma_scale_f32_32x32x64_f8f6f4(
              a8[mt], b8[nt], acc[mt][nt], 0, 0, 0, 127u, 0, 127u);
    }
    __syncthreads();
  }

  const int ch = ((n0 + wn) >> 6) * 32 + l32;
  const float2 c2 = *(const float2*)(cs + (long)bzs * 2048 + ch * 2);  // (csZ, csK)
#pragma unroll
  for (int mt = 0; mt < 2; ++mt) {
    const long ttile = (long)(bzs * 2048 + m0 + wm + mt * 32) >> 5;
    const long qbase = (ttile * 32 + ((n0 + wn) >> 6)) * 1024;
#pragma unroll
    for (int q = 0; q < 4; ++q) {
      const half4v qv = *(const half4v*)(Qsig + qbase + q * 256 + lane * 4);
#pragma unroll
      for (int rr = 0; rr < 4; ++rr) {
        const int reg = q * 4 + rr;
        const float num = c2.x + acc[mt][0][reg] * 0.125f;
        const float den = c2.y + acc[mt][1][reg] * 0.125f;
        const int r = m0 + wm + mt * 32 + 4 * khalf + 8 * q + rr;
        const int R = bzs * 2048 + r;
        const long off = ((long)(R >> 7) * 16 + (ch >> 6)) * 8192 + frag_off(R & 127, ch & 63);
        OH[off] = (_Float16)((float)qv[rr] * num / den);
      }
    }
  }
}

// ---------------- launch ----------------
extern "C" void kernel_launch(void* const* d_in, const int* in_sizes, int n_in, void* d_out,
                              int out_size, void* d_ws, size_t ws_size, hipStream_t stream) {
  const float* x = (const float*)d_in[0];
  const float* Wq = (const float*)d_in[1];
  const float* bq = (const float*)d_in[2];
  const float* Wk = (const float*)d_in[3];
  const float* bk = (const float*)d_in[4];
  const float* Wv = (const float*)d_in[5];
  const float* bv = (const float*)d_in[6];
  const float* Wo = (const float*)d_in[7];
  const float* bo = (const float*)d_in[8];
  const float* wb = (const float*)d_in[9];

  char* ws = (char*)d_ws;
  _Float16* x_h = (_Float16*)(ws + 0);              // 16 MB  (1024 f16 frag tiles)
  _Float16* WqkvT = (_Float16*)(ws + 16777216);     //  6 MB
  _Float16* WoT = (_Float16*)(ws + 23068672);       //  2 MB
  char* E8 = (char*)(ws + 25165824);                //  4 MB  (256 fp8 frag tiles)
  _Float16* Qsig = (_Float16*)(ws + 29360128);      // 16 MB  (C-frag tiles)
  char* Zt8 = (char*)(ws + 46137344);               // 16 MB  (fp8 frag tiles, 4 batches)
  _Float16* OutHead = (_Float16*)(ws + 62914560);   // 16 MB  (f16 frag tiles)
  float* cs = (float*)(ws + 79691776);              // 32 KB  (csZ,csK interleaved)

  hipMemsetAsync(cs, 0, 4 * 2048 * sizeof(float), stream);

  // prep: x tiles + weight tiles + E8 tiles
  prep_all<<<1792, 256, 0, stream>>>(x, wb, Wq, Wk, Wv, Wo, x_h, E8, WqkvT, WoT);

  // GEMM1: x @ [Wq|Wkv]; epilogue -> Qsig (C-frag), Zt8 (fp8), colsum atomics
  gemm_bt<0><<<dim3(64, 24), 256, 0, stream>>>(x_h, WqkvT, Qsig, 16, bq, bk, bv, Zt8, cs);

  // GEMM2 (fp8 correction + rank-1): OutHead = Qsig*(csZ+E@Z)/(csK+E@eK)
  gemm2_fp8<<<dim3(16, 16, 4), 256, 0, stream>>>(E8, Zt8, OutHead, Qsig, cs);

  // GEMM3: out = OutHead @ Wo + bo (fp32)
  gemm_bt<2><<<dim3(64, 8), 256, 0, stream>>>(OutHead, WoT, d_out, 16, bo, nullptr, nullptr,
                                              nullptr, nullptr);
}